// Round 1
// baseline (1387.160 us; speedup 1.0000x reference)
//
#include <hip/hip_runtime.h>
#include <hip/hip_bf16.h>
#include <math.h>

// SSD post-processing for MI355X.
// Stages: (1) softmax->fg scores [B][7][A]; (2) per-(b,c) top-200 via radix-select
// + bitonic sort; (3) gather+decode selected boxes; (4) per-image class-aware
// greedy NMS + top-200 output.

#define NCLS 8
#define NFG 7
#define TOPK 200
#define NMSM (NFG * TOPK)   // 1400
#define LOW_SCORE 0.01f
#define NMS_THR 0.45f
#define BINS 4096
#define CAP 4096

// ---------------- stage 1: softmax + transpose ----------------
__global__ __launch_bounds__(256) void score_kernel(
    const float* __restrict__ logits, float* __restrict__ scores, int A, int total) {
  int i = blockIdx.x * 256 + threadIdx.x;   // i = b*A + a
  if (i >= total) return;
  int b = i / A;
  int a = i - b * A;
  const float* p = logits + (size_t)i * NCLS;
  float x[NCLS];
#pragma unroll
  for (int c = 0; c < NCLS; c++) x[c] = p[c];
  float mx = x[0];
#pragma unroll
  for (int c = 1; c < NCLS; c++) mx = fmaxf(mx, x[c]);
  float e[NCLS];
  float s = 0.0f;
#pragma unroll
  for (int c = 0; c < NCLS; c++) { e[c] = expf(x[c] - mx); s += e[c]; }
  float inv = 1.0f / s;
#pragma unroll
  for (int c = 1; c < NCLS; c++) {
    scores[((size_t)b * NFG + (c - 1)) * A + a] = e[c] * inv;
  }
}

// ---------------- bitonic sort (descending) on shared ulong ----------------
__device__ inline void bitonic_desc(unsigned long long* buf, int P, int tid, int nthr) {
  for (int k = 2; k <= P; k <<= 1) {
    for (int j = k >> 1; j > 0; j >>= 1) {
      __syncthreads();
      for (int i = tid; i < P; i += nthr) {
        int l = i ^ j;
        if (l > i) {
          unsigned long long va = buf[i], vb = buf[l];
          bool descRegion = ((i & k) == 0);
          if (descRegion ? (va < vb) : (va > vb)) { buf[i] = vb; buf[l] = va; }
        }
      }
    }
  }
  __syncthreads();
}

// ---------------- stage 2: per-(b,c) top-K ----------------
__global__ __launch_bounds__(256) void topk_kernel(
    const float* __restrict__ scores, int A,
    float* __restrict__ tval, int* __restrict__ tidx) {
  __shared__ unsigned int hist[BINS];
  __shared__ unsigned long long buf[CAP];
  __shared__ int s_t, s_cnt;
  int tid = threadIdx.x;
  int row = blockIdx.x;  // b*7 + c
  const float* p = scores + (size_t)row * A;

  for (int i = tid; i < BINS; i += 256) hist[i] = 0;
  __syncthreads();
  for (int a = tid; a < A; a += 256) {
    unsigned key = __float_as_uint(p[a]);  // scores in (0,1): positive -> order-preserving
    atomicAdd(&hist[key >> 19], 1u);
  }
  __syncthreads();
  if (tid == 0) {
    unsigned cum = 0;
    int t = BINS - 1;
    for (; t >= 0; t--) { cum += hist[t]; if (cum >= TOPK) break; }
    if (t < 0) t = 0;
    s_t = t;
    s_cnt = 0;
  }
  __syncthreads();
  unsigned tbin = (unsigned)s_t;
  for (int a = tid; a < A; a += 256) {
    unsigned key = __float_as_uint(p[a]);
    if ((key >> 19) >= tbin) {
      int pos = atomicAdd(&s_cnt, 1);
      if (pos < CAP)
        buf[pos] = ((unsigned long long)key << 32) | (unsigned)(~a);
    }
  }
  __syncthreads();
  int cnt = s_cnt; if (cnt > CAP) cnt = CAP;
  int P = 256; while (P < cnt) P <<= 1;
  for (int i = cnt + tid; i < P; i += 256) buf[i] = 0ull;
  __syncthreads();
  bitonic_desc(buf, P, tid, 256);
  if (tid < TOPK) {
    unsigned long long v = buf[tid];
    tval[(size_t)row * TOPK + tid] = __uint_as_float((unsigned)(v >> 32));
    tidx[(size_t)row * TOPK + tid] = (int)(~(unsigned)(v & 0xFFFFFFFFull));
  }
}

// ---------------- stage 3: gather + decode ----------------
__global__ __launch_bounds__(256) void gather_kernel(
    const float* __restrict__ deltas, const float* __restrict__ dbox,
    const float* __restrict__ tval, const int* __restrict__ tidx,
    float* __restrict__ cboxes, float* __restrict__ cscores, int A, int total) {
  int i = blockIdx.x * 256 + threadIdx.x;  // b*NMSM + m
  if (i >= total) return;
  int b = i / NMSM;
  int m = i - b * NMSM;
  int c = m / TOPK;
  int r = m - c * TOPK;
  size_t tk = ((size_t)b * NFG + c) * TOPK + r;
  int a = tidx[tk];
  float v = tval[tk];
  const float* db = dbox + (size_t)a * 4;
  float w = db[2] - db[0];
  float h = db[3] - db[1];
  float cx = db[0] + 0.5f * w;
  float cy = db[1] + 0.5f * h;
  const float* dd = deltas + ((size_t)b * A + a) * 4;
  float pcx = dd[0] / 10.0f * w + cx;
  float pcy = dd[1] / 10.0f * h + cy;
  float pw = expf(dd[2] / 5.0f) * w;
  float ph = expf(dd[3] / 5.0f) * h;
  float x0 = fminf(fmaxf(pcx - 0.5f * pw, 0.0f), 1.0f);
  float y0 = fminf(fmaxf(pcy - 0.5f * ph, 0.0f), 1.0f);
  float x1 = fminf(fmaxf(pcx + 0.5f * pw, 0.0f), 1.0f);
  float y1 = fminf(fmaxf(pcy + 0.5f * ph, 0.0f), 1.0f);
  float* cb = cboxes + (size_t)i * 4;
  cb[0] = x0; cb[1] = y0; cb[2] = x1; cb[3] = y1;
  cscores[i] = v;
}

// ---------------- stage 4: per-image NMS + output ----------------
__global__ __launch_bounds__(256) void nms_kernel(
    const float* __restrict__ cboxes, const float* __restrict__ cscores,
    float* __restrict__ out, int B) {
  __shared__ unsigned long long sbuf[2048];
  __shared__ float bx0[NMSM], by0[NMSM], bx1[NMSM], by1[NMSM], ar[NMSM];
  __shared__ short ordm[NMSM];
  __shared__ short rank[NMSM];
  __shared__ unsigned char keep[NMSM];
  int tid = threadIdx.x;
  int b = blockIdx.x;
  const float* sc = cscores + (size_t)b * NMSM;

  // sort candidates by (score desc, index asc); entries <= LOW_SCORE get key 0
  for (int i = tid; i < 2048; i += 256) {
    unsigned long long v = 0ull;
    if (i < NMSM) {
      float s = sc[i];
      unsigned key = (s > LOW_SCORE) ? __float_as_uint(s) : 0u;
      v = ((unsigned long long)key << 32) | (unsigned)(~i);
    }
    sbuf[i] = v;
  }
  bitonic_desc(sbuf, 2048, tid, 256);

  for (int i = tid; i < NMSM; i += 256) {
    unsigned long long v = sbuf[i];
    unsigned key = (unsigned)(v >> 32);
    int m = (int)(~(unsigned)(v & 0xFFFFFFFFull));
    ordm[i] = (short)m;
    keep[i] = (key != 0u) ? 1 : 0;
    const float* cb = cboxes + ((size_t)b * NMSM + m) * 4;
    float off = 4.0f * (float)(m / TOPK + 1);   // class offset; labels 1..7
    float x0 = cb[0] + off, y0 = cb[1] + off, x1 = cb[2] + off, y1 = cb[3] + off;
    bx0[i] = x0; by0[i] = y0; bx1[i] = x1; by1[i] = y1;
    ar[i] = (x1 - x0) * (y1 - y0);
  }
  __syncthreads();

  // greedy suppression (matches reference scan semantics)
  for (int i = 0; i < NMSM; i++) {
    __syncthreads();
    if (!keep[i]) continue;
    float xi0 = bx0[i], yi0 = by0[i], xi1 = bx1[i], yi1 = by1[i], ai = ar[i];
    for (int j = i + 1 + tid; j < NMSM; j += 256) {
      if (!keep[j]) continue;
      float xl = fmaxf(xi0, bx0[j]);
      float yt = fmaxf(yi0, by0[j]);
      float xr = fminf(xi1, bx1[j]);
      float yb = fminf(yi1, by1[j]);
      float inter = fmaxf(xr - xl, 0.0f) * fmaxf(yb - yt, 0.0f);
      float iou = inter / (ai + ar[j] - inter);   // NaN (0/0) -> not suppressed
      if (iou > NMS_THR) keep[j] = 0;
    }
  }
  __syncthreads();

  if (tid == 0) {
    int r = 0;
    for (int i = 0; i < NMSM; i++) rank[i] = keep[i] ? (short)(r++) : (short)9999;
  }
  __syncthreads();

  // outputs: boxes [B,200,4] | scores [B,200] | labels [B,200] (flat f32)
  float* ob = out + (size_t)b * TOPK * 4;
  float* os = out + (size_t)B * TOPK * 4 + (size_t)b * TOPK;
  float* ol = out + (size_t)B * TOPK * 5 + (size_t)b * TOPK;
  for (int r = tid; r < TOPK; r += 256) {
    ob[r * 4 + 0] = 0.0f; ob[r * 4 + 1] = 0.0f; ob[r * 4 + 2] = 0.0f; ob[r * 4 + 3] = 0.0f;
    os[r] = 0.0f;
    ol[r] = 0.0f;
  }
  __syncthreads();
  for (int i = tid; i < NMSM; i += 256) {
    int r = rank[i];
    if (r < TOPK) {
      int m = ordm[i];
      const float* cb = cboxes + ((size_t)b * NMSM + m) * 4;
      ob[r * 4 + 0] = cb[0]; ob[r * 4 + 1] = cb[1];
      ob[r * 4 + 2] = cb[2]; ob[r * 4 + 3] = cb[3];
      os[r] = sc[m];
      ol[r] = (float)(m / TOPK + 1);
    }
  }
}

extern "C" void kernel_launch(void* const* d_in, const int* in_sizes, int n_in,
                              void* d_out, int out_size, void* d_ws, size_t ws_size,
                              hipStream_t stream) {
  const float* logits = (const float*)d_in[0];
  const float* deltas = (const float*)d_in[1];
  const float* dbox   = (const float*)d_in[2];
  int A = in_sizes[2] / 4;
  int B = in_sizes[0] / (A * NCLS);
  float* out = (float*)d_out;

  // workspace layout
  float* scores_ws = (float*)d_ws;                                  // B*7*A
  float* tval = scores_ws + (size_t)B * NFG * A;                    // B*7*200
  int*   tidx = (int*)(tval + (size_t)B * NFG * TOPK);              // B*7*200
  float* cboxes = (float*)(tidx + (size_t)B * NFG * TOPK);          // B*1400*4
  float* cscores = cboxes + (size_t)B * NMSM * 4;                   // B*1400

  int total = B * A;
  score_kernel<<<(total + 255) / 256, 256, 0, stream>>>(logits, scores_ws, A, total);
  topk_kernel<<<B * NFG, 256, 0, stream>>>(scores_ws, A, tval, tidx);
  int gtotal = B * NMSM;
  gather_kernel<<<(gtotal + 255) / 256, 256, 0, stream>>>(deltas, dbox, tval, tidx,
                                                          cboxes, cscores, A, gtotal);
  nms_kernel<<<B, 256, 0, stream>>>(cboxes, cscores, out, B);
}

// Round 2
// 891.441 us; speedup vs baseline: 1.5561x; 1.5561x over previous
//
#include <hip/hip_runtime.h>
#include <hip/hip_bf16.h>
#include <math.h>

// SSD post-processing for MI355X.
// (1) softmax->fg scores [B][7][A]; (2) per-(b,c) top-200 radix-select+bitonic;
// (3) gather+decode selected boxes; (4) NMS: sort -> parallel IoU bitmask ->
// single-wave serial reduce with prefetch ring -> top-200 output.

#define NCLS 8
#define NFG 7
#define TOPK 200
#define NMSM (NFG * TOPK)   // 1400
#define NCH 22              // ceil(1400/64) 64-wide chunks
#define NPAIRS (NCH * (NCH + 1) / 2)  // 253 upper-triangle chunk pairs
#define LOW_SCORE 0.01f
#define NMS_THR 0.45f
#define BINS 4096
#define CAP 4096

// ---------------- stage 1: softmax + transpose ----------------
__global__ __launch_bounds__(256) void score_kernel(
    const float* __restrict__ logits, float* __restrict__ scores, int A, int total) {
  int i = blockIdx.x * 256 + threadIdx.x;   // i = b*A + a
  if (i >= total) return;
  int b = i / A;
  int a = i - b * A;
  const float* p = logits + (size_t)i * NCLS;
  float x[NCLS];
#pragma unroll
  for (int c = 0; c < NCLS; c++) x[c] = p[c];
  float mx = x[0];
#pragma unroll
  for (int c = 1; c < NCLS; c++) mx = fmaxf(mx, x[c]);
  float e[NCLS];
  float s = 0.0f;
#pragma unroll
  for (int c = 0; c < NCLS; c++) { e[c] = expf(x[c] - mx); s += e[c]; }
  float inv = 1.0f / s;
#pragma unroll
  for (int c = 1; c < NCLS; c++) {
    scores[((size_t)b * NFG + (c - 1)) * A + a] = e[c] * inv;
  }
}

// ---------------- bitonic sort (descending) on shared ulong ----------------
__device__ inline void bitonic_desc(unsigned long long* buf, int P, int tid, int nthr) {
  for (int k = 2; k <= P; k <<= 1) {
    for (int j = k >> 1; j > 0; j >>= 1) {
      __syncthreads();
      for (int i = tid; i < P; i += nthr) {
        int l = i ^ j;
        if (l > i) {
          unsigned long long va = buf[i], vb = buf[l];
          bool descRegion = ((i & k) == 0);
          if (descRegion ? (va < vb) : (va > vb)) { buf[i] = vb; buf[l] = va; }
        }
      }
    }
  }
  __syncthreads();
}

// ---------------- stage 2: per-(b,c) top-K ----------------
__global__ __launch_bounds__(256) void topk_kernel(
    const float* __restrict__ scores, int A,
    float* __restrict__ tval, int* __restrict__ tidx) {
  __shared__ unsigned int hist[BINS];
  __shared__ unsigned long long buf[CAP];
  __shared__ int s_t, s_cnt;
  int tid = threadIdx.x;
  int row = blockIdx.x;  // b*7 + c
  const float* p = scores + (size_t)row * A;

  for (int i = tid; i < BINS; i += 256) hist[i] = 0;
  __syncthreads();
  for (int a = tid; a < A; a += 256) {
    unsigned key = __float_as_uint(p[a]);  // scores in (0,1): positive -> order-preserving
    atomicAdd(&hist[key >> 19], 1u);
  }
  __syncthreads();
  if (tid == 0) {
    unsigned cum = 0;
    int t = BINS - 1;
    for (; t >= 0; t--) { cum += hist[t]; if (cum >= TOPK) break; }
    if (t < 0) t = 0;
    s_t = t;
    s_cnt = 0;
  }
  __syncthreads();
  unsigned tbin = (unsigned)s_t;
  for (int a = tid; a < A; a += 256) {
    unsigned key = __float_as_uint(p[a]);
    if ((key >> 19) >= tbin) {
      int pos = atomicAdd(&s_cnt, 1);
      if (pos < CAP)
        buf[pos] = ((unsigned long long)key << 32) | (unsigned)(~a);
    }
  }
  __syncthreads();
  int cnt = s_cnt; if (cnt > CAP) cnt = CAP;
  int P = 256; while (P < cnt) P <<= 1;
  for (int i = cnt + tid; i < P; i += 256) buf[i] = 0ull;
  __syncthreads();
  bitonic_desc(buf, P, tid, 256);
  if (tid < TOPK) {
    unsigned long long v = buf[tid];
    tval[(size_t)row * TOPK + tid] = __uint_as_float((unsigned)(v >> 32));
    tidx[(size_t)row * TOPK + tid] = (int)(~(unsigned)(v & 0xFFFFFFFFull));
  }
}

// ---------------- stage 3: gather + decode ----------------
__global__ __launch_bounds__(256) void gather_kernel(
    const float* __restrict__ deltas, const float* __restrict__ dbox,
    const float* __restrict__ tval, const int* __restrict__ tidx,
    float* __restrict__ cboxes, float* __restrict__ cscores, int A, int total) {
  int i = blockIdx.x * 256 + threadIdx.x;  // b*NMSM + m
  if (i >= total) return;
  int b = i / NMSM;
  int m = i - b * NMSM;
  int c = m / TOPK;
  int r = m - c * TOPK;
  size_t tk = ((size_t)b * NFG + c) * TOPK + r;
  int a = tidx[tk];
  float v = tval[tk];
  const float* db = dbox + (size_t)a * 4;
  float w = db[2] - db[0];
  float h = db[3] - db[1];
  float cx = db[0] + 0.5f * w;
  float cy = db[1] + 0.5f * h;
  const float* dd = deltas + ((size_t)b * A + a) * 4;
  float pcx = dd[0] / 10.0f * w + cx;
  float pcy = dd[1] / 10.0f * h + cy;
  float pw = expf(dd[2] / 5.0f) * w;
  float ph = expf(dd[3] / 5.0f) * h;
  float x0 = fminf(fmaxf(pcx - 0.5f * pw, 0.0f), 1.0f);
  float y0 = fminf(fmaxf(pcy - 0.5f * ph, 0.0f), 1.0f);
  float x1 = fminf(fmaxf(pcx + 0.5f * pw, 0.0f), 1.0f);
  float y1 = fminf(fmaxf(pcy + 0.5f * ph, 0.0f), 1.0f);
  float* cb = cboxes + (size_t)i * 4;
  cb[0] = x0; cb[1] = y0; cb[2] = x1; cb[3] = y1;
  cscores[i] = v;
}

// ---------------- stage 4a: per-image sort ----------------
__global__ __launch_bounds__(256) void nms_sort_kernel(
    const float* __restrict__ cboxes, const float* __restrict__ cscores,
    float* __restrict__ sx0, float* __restrict__ sy0,
    float* __restrict__ sx1, float* __restrict__ sy1,
    float* __restrict__ sar, int* __restrict__ sord, int* __restrict__ nvalid) {
  __shared__ unsigned long long sbuf[2048];
  __shared__ int s_cnt;
  int tid = threadIdx.x;
  int b = blockIdx.x;
  const float* sc = cscores + (size_t)b * NMSM;
  if (tid == 0) s_cnt = 0;
  __syncthreads();
  int myv = 0;
  for (int i = tid; i < 2048; i += 256) {
    unsigned long long v = 0ull;
    if (i < NMSM) {
      float s = sc[i];
      unsigned key = (s > LOW_SCORE) ? __float_as_uint(s) : 0u;
      if (key) myv++;
      v = ((unsigned long long)key << 32) | (unsigned)(~i);
    }
    sbuf[i] = v;
  }
  if (myv) atomicAdd(&s_cnt, myv);
  bitonic_desc(sbuf, 2048, tid, 256);
  size_t base = (size_t)b * NMSM;
  for (int i = tid; i < NMSM; i += 256) {
    unsigned long long v = sbuf[i];
    int m = (int)(~(unsigned)(v & 0xFFFFFFFFull));
    sord[base + i] = m;
    const float* cb = cboxes + (base + m) * 4;
    float off = 4.0f * (float)(m / TOPK + 1);
    float x0 = cb[0] + off, y0 = cb[1] + off, x1 = cb[2] + off, y1 = cb[3] + off;
    sx0[base + i] = x0; sy0[base + i] = y0;
    sx1[base + i] = x1; sy1[base + i] = y1;
    sar[base + i] = (x1 - x0) * (y1 - y0);
  }
  if (tid == 0) nvalid[b] = s_cnt;
}

// ---------------- stage 4b: suppression bitmask ----------------
__global__ __launch_bounds__(64) void nms_mask_kernel(
    const float* __restrict__ sx0, const float* __restrict__ sy0,
    const float* __restrict__ sx1, const float* __restrict__ sy1,
    const float* __restrict__ sar, unsigned long long* __restrict__ mask) {
  int b = blockIdx.y;
  int pair = blockIdx.x;
  int ci = 0, rem = pair;
  while (rem >= NCH - ci) { rem -= NCH - ci; ci++; }
  int cj = ci + rem;   // cj >= ci (upper triangle)
  __shared__ float cx0[64], cy0[64], cx1[64], cy1[64], car[64];
  int t = threadIdx.x;
  size_t base = (size_t)b * NMSM;
  int j = cj * 64 + t;
  if (j < NMSM) {
    cx0[t] = sx0[base + j]; cy0[t] = sy0[base + j];
    cx1[t] = sx1[base + j]; cy1[t] = sy1[base + j];
    car[t] = sar[base + j];
  }
  __syncthreads();
  int i = ci * 64 + t;
  if (i >= NMSM) return;
  float x0 = sx0[base + i], y0 = sy0[base + i];
  float x1 = sx1[base + i], y1 = sy1[base + i], a = sar[base + i];
  unsigned long long bits = 0ull;
#pragma unroll 8
  for (int jj = 0; jj < 64; jj++) {
    int jg = cj * 64 + jj;
    float xl = fmaxf(x0, cx0[jj]);
    float yt = fmaxf(y0, cy0[jj]);
    float xr = fminf(x1, cx1[jj]);
    float yb = fminf(y1, cy1[jj]);
    float inter = fmaxf(xr - xl, 0.0f) * fmaxf(yb - yt, 0.0f);
    float iou = inter / (a + car[jj] - inter);
    if (jg > i && jg < NMSM && iou > NMS_THR) bits |= 1ull << jj;
  }
  mask[(base + i) * NCH + cj] = bits;
}

// ---------------- stage 4c: serial greedy reduce + output ----------------
__global__ __launch_bounds__(64) void nms_serial_kernel(
    const unsigned long long* __restrict__ mask, const int* __restrict__ sord,
    const int* __restrict__ nvalidArr,
    const float* __restrict__ cboxes, const float* __restrict__ cscores,
    float* __restrict__ out, int B) {
  __shared__ unsigned long long skeep[NCH];
  __shared__ int spfx[NCH];
  int b = blockIdx.x;
  int lane = threadIdx.x;
  int nvalid = nvalidArr[b];
  const unsigned long long* M = mask + (size_t)b * NMSM * NCH;

  // init remove: bit set for sorted positions < nvalid
  unsigned long long remove = 0ull;
  if (lane < NCH) {
    int base = lane * 64;
    if (base + 64 <= nvalid) remove = ~0ull;
    else if (base < nvalid) remove = (~0ull) >> (64 - (nvalid - base));
  }

  // 8-deep prefetch ring: lane w holds word w of rows i..i+7
  unsigned long long ring[8];
#pragma unroll
  for (int d = 0; d < 8; d++)
    ring[d] = (lane < NCH) ? M[(size_t)d * NCH + lane] : 0ull;

  for (int i = 0; i < NMSM; i++) {
    unsigned long long w = __shfl(remove, i >> 6);
    bool kept = (w >> (i & 63)) & 1ull;
    unsigned long long row = ring[i & 7];
    int nx = i + 8;
    if (lane < NCH && nx < NMSM) ring[i & 7] = M[(size_t)nx * NCH + lane];
    if (kept && lane < NCH && lane >= (i >> 6)) remove &= ~row;
  }

  if (lane < NCH) skeep[lane] = remove;
  __syncthreads();
  if (lane == 0) {
    int s = 0;
    for (int w = 0; w < NCH; w++) { spfx[w] = s; s += __popcll(skeep[w]); }
  }
  __syncthreads();

  float* ob = out + (size_t)b * TOPK * 4;
  float* os = out + (size_t)B * TOPK * 4 + (size_t)b * TOPK;
  float* ol = out + (size_t)B * TOPK * 5 + (size_t)b * TOPK;
  for (int r = lane; r < TOPK; r += 64) {
    ob[r * 4 + 0] = 0.0f; ob[r * 4 + 1] = 0.0f;
    ob[r * 4 + 2] = 0.0f; ob[r * 4 + 3] = 0.0f;
    os[r] = 0.0f; ol[r] = 0.0f;
  }
  __syncthreads();
  size_t base = (size_t)b * NMSM;
  for (int i = lane; i < NMSM; i += 64) {
    int w = i >> 6;
    unsigned long long kw = skeep[w];
    if ((kw >> (i & 63)) & 1ull) {
      int r = spfx[w] + __popcll(kw & ((1ull << (i & 63)) - 1ull));
      if (r < TOPK) {
        int m = sord[base + i];
        const float* cb = cboxes + (base + m) * 4;
        ob[r * 4 + 0] = cb[0]; ob[r * 4 + 1] = cb[1];
        ob[r * 4 + 2] = cb[2]; ob[r * 4 + 3] = cb[3];
        os[r] = cscores[base + m];
        ol[r] = (float)(m / TOPK + 1);
      }
    }
  }
}

extern "C" void kernel_launch(void* const* d_in, const int* in_sizes, int n_in,
                              void* d_out, int out_size, void* d_ws, size_t ws_size,
                              hipStream_t stream) {
  const float* logits = (const float*)d_in[0];
  const float* deltas = (const float*)d_in[1];
  const float* dbox   = (const float*)d_in[2];
  int A = in_sizes[2] / 4;
  int B = in_sizes[0] / (A * NCLS);
  float* out = (float*)d_out;

  // workspace layout
  float* scores_ws = (float*)d_ws;                                  // B*7*A floats
  float* tval = scores_ws + (size_t)B * NFG * A;                    // B*7*200
  int*   tidx = (int*)(tval + (size_t)B * NFG * TOPK);              // B*7*200
  float* cboxes = (float*)(tidx + (size_t)B * NFG * TOPK);          // B*1400*4
  float* cscores = cboxes + (size_t)B * NMSM * 4;                   // B*1400

  // NMS scratch aliased onto the scores buffer (dead after topk_kernel):
  //   mask: B*1400*22 u64 = 7.88 MB at offset 0
  //   sorted arrays at +8 MB (2,097,152 floats)
  unsigned long long* mask = (unsigned long long*)scores_ws;
  float* sbase = scores_ws + 2097152;
  size_t n1 = (size_t)B * NMSM;
  float* sx0 = sbase;            float* sy0 = sbase + n1;
  float* sx1 = sbase + 2 * n1;   float* sy1 = sbase + 3 * n1;
  float* sar = sbase + 4 * n1;
  int*   sord = (int*)(sbase + 5 * n1);
  int*   nvalid = (int*)(sbase + 6 * n1);

  int total = B * A;
  score_kernel<<<(total + 255) / 256, 256, 0, stream>>>(logits, scores_ws, A, total);
  topk_kernel<<<B * NFG, 256, 0, stream>>>(scores_ws, A, tval, tidx);
  int gtotal = B * NMSM;
  gather_kernel<<<(gtotal + 255) / 256, 256, 0, stream>>>(deltas, dbox, tval, tidx,
                                                          cboxes, cscores, A, gtotal);
  nms_sort_kernel<<<B, 256, 0, stream>>>(cboxes, cscores, sx0, sy0, sx1, sy1, sar,
                                         sord, nvalid);
  nms_mask_kernel<<<dim3(NPAIRS, B), 64, 0, stream>>>(sx0, sy0, sx1, sy1, sar, mask);
  nms_serial_kernel<<<B, 64, 0, stream>>>(mask, sord, nvalid, cboxes, cscores, out, B);
}

// Round 4
// 780.051 us; speedup vs baseline: 1.7783x; 1.1428x over previous
//
#include <hip/hip_runtime.h>
#include <hip/hip_bf16.h>
#include <math.h>

// SSD post-processing for MI355X.
// (1) softmax->fg scores [B][7][A]; (2) per-(b,c) top-200 radix-select+bitonic;
// (3) gather+decode selected boxes; (4) NMS: sort -> parallel IoU bitmask ->
// single-wave serial reduce (32-deep static register prefetch ring) -> top-200.

#define NCLS 8
#define NFG 7
#define TOPK 200
#define NMSM (NFG * TOPK)   // 1400
#define NCH 22              // ceil(1400/64) 64-wide chunks
#define NPAIRS (NCH * (NCH + 1) / 2)  // 253 upper-triangle chunk pairs
#define RING 32             // prefetch depth (static indices -> registers)
#define LOW_SCORE 0.01f
#define NMS_THR 0.45f
#define BINS 4096
#define CAP 4096

// ---------------- stage 1: softmax + transpose ----------------
__global__ __launch_bounds__(256) void score_kernel(
    const float* __restrict__ logits, float* __restrict__ scores, int A, int total) {
  int i = blockIdx.x * 256 + threadIdx.x;   // i = b*A + a
  if (i >= total) return;
  int b = i / A;
  int a = i - b * A;
  const float* p = logits + (size_t)i * NCLS;
  float x[NCLS];
#pragma unroll
  for (int c = 0; c < NCLS; c++) x[c] = p[c];
  float mx = x[0];
#pragma unroll
  for (int c = 1; c < NCLS; c++) mx = fmaxf(mx, x[c]);
  float e[NCLS];
  float s = 0.0f;
#pragma unroll
  for (int c = 0; c < NCLS; c++) { e[c] = expf(x[c] - mx); s += e[c]; }
  float inv = 1.0f / s;
#pragma unroll
  for (int c = 1; c < NCLS; c++) {
    scores[((size_t)b * NFG + (c - 1)) * A + a] = e[c] * inv;
  }
}

// ---------------- bitonic sort (descending) on shared ulong ----------------
__device__ inline void bitonic_desc(unsigned long long* buf, int P, int tid, int nthr) {
  for (int k = 2; k <= P; k <<= 1) {
    for (int j = k >> 1; j > 0; j >>= 1) {
      __syncthreads();
      for (int i = tid; i < P; i += nthr) {
        int l = i ^ j;
        if (l > i) {
          unsigned long long va = buf[i], vb = buf[l];
          bool descRegion = ((i & k) == 0);
          if (descRegion ? (va < vb) : (va > vb)) { buf[i] = vb; buf[l] = va; }
        }
      }
    }
  }
  __syncthreads();
}

// ---------------- stage 2: per-(b,c) top-K ----------------
__global__ __launch_bounds__(256) void topk_kernel(
    const float* __restrict__ scores, int A,
    float* __restrict__ tval, int* __restrict__ tidx) {
  __shared__ unsigned int hist[BINS];
  __shared__ unsigned long long buf[CAP];
  __shared__ int s_t, s_cnt;
  int tid = threadIdx.x;
  int row = blockIdx.x;  // b*7 + c
  const float* p = scores + (size_t)row * A;

  for (int i = tid; i < BINS; i += 256) hist[i] = 0;
  __syncthreads();
  for (int a = tid; a < A; a += 256) {
    unsigned key = __float_as_uint(p[a]);  // scores in (0,1): positive -> order-preserving
    atomicAdd(&hist[key >> 19], 1u);
  }
  __syncthreads();
  if (tid == 0) {
    unsigned cum = 0;
    int t = BINS - 1;
    for (; t >= 0; t--) { cum += hist[t]; if (cum >= TOPK) break; }
    if (t < 0) t = 0;
    s_t = t;
    s_cnt = 0;
  }
  __syncthreads();
  unsigned tbin = (unsigned)s_t;
  for (int a = tid; a < A; a += 256) {
    unsigned key = __float_as_uint(p[a]);
    if ((key >> 19) >= tbin) {
      int pos = atomicAdd(&s_cnt, 1);
      if (pos < CAP)
        buf[pos] = ((unsigned long long)key << 32) | (unsigned)(~a);
    }
  }
  __syncthreads();
  int cnt = s_cnt; if (cnt > CAP) cnt = CAP;
  int P = 256; while (P < cnt) P <<= 1;
  for (int i = cnt + tid; i < P; i += 256) buf[i] = 0ull;
  __syncthreads();
  bitonic_desc(buf, P, tid, 256);
  if (tid < TOPK) {
    unsigned long long v = buf[tid];
    tval[(size_t)row * TOPK + tid] = __uint_as_float((unsigned)(v >> 32));
    tidx[(size_t)row * TOPK + tid] = (int)(~(unsigned)(v & 0xFFFFFFFFull));
  }
}

// ---------------- stage 3: gather + decode ----------------
__global__ __launch_bounds__(256) void gather_kernel(
    const float* __restrict__ deltas, const float* __restrict__ dbox,
    const float* __restrict__ tval, const int* __restrict__ tidx,
    float* __restrict__ cboxes, float* __restrict__ cscores, int A, int total) {
  int i = blockIdx.x * 256 + threadIdx.x;  // b*NMSM + m
  if (i >= total) return;
  int b = i / NMSM;
  int m = i - b * NMSM;
  int c = m / TOPK;
  int r = m - c * TOPK;
  size_t tk = ((size_t)b * NFG + c) * TOPK + r;
  int a = tidx[tk];
  float v = tval[tk];
  const float* db = dbox + (size_t)a * 4;
  float w = db[2] - db[0];
  float h = db[3] - db[1];
  float cx = db[0] + 0.5f * w;
  float cy = db[1] + 0.5f * h;
  const float* dd = deltas + ((size_t)b * A + a) * 4;
  float pcx = dd[0] / 10.0f * w + cx;
  float pcy = dd[1] / 10.0f * h + cy;
  float pw = expf(dd[2] / 5.0f) * w;
  float ph = expf(dd[3] / 5.0f) * h;
  float x0 = fminf(fmaxf(pcx - 0.5f * pw, 0.0f), 1.0f);
  float y0 = fminf(fmaxf(pcy - 0.5f * ph, 0.0f), 1.0f);
  float x1 = fminf(fmaxf(pcx + 0.5f * pw, 0.0f), 1.0f);
  float y1 = fminf(fmaxf(pcy + 0.5f * ph, 0.0f), 1.0f);
  float* cb = cboxes + (size_t)i * 4;
  cb[0] = x0; cb[1] = y0; cb[2] = x1; cb[3] = y1;
  cscores[i] = v;
}

// ---------------- stage 4a: per-image sort ----------------
__global__ __launch_bounds__(256) void nms_sort_kernel(
    const float* __restrict__ cboxes, const float* __restrict__ cscores,
    float* __restrict__ sx0, float* __restrict__ sy0,
    float* __restrict__ sx1, float* __restrict__ sy1,
    float* __restrict__ sar, int* __restrict__ sord, int* __restrict__ nvalid) {
  __shared__ unsigned long long sbuf[2048];
  __shared__ int s_cnt;
  int tid = threadIdx.x;
  int b = blockIdx.x;
  const float* sc = cscores + (size_t)b * NMSM;
  if (tid == 0) s_cnt = 0;
  __syncthreads();
  int myv = 0;
  for (int i = tid; i < 2048; i += 256) {
    unsigned long long v = 0ull;
    if (i < NMSM) {
      float s = sc[i];
      unsigned key = (s > LOW_SCORE) ? __float_as_uint(s) : 0u;
      if (key) myv++;
      v = ((unsigned long long)key << 32) | (unsigned)(~i);
    }
    sbuf[i] = v;
  }
  if (myv) atomicAdd(&s_cnt, myv);
  bitonic_desc(sbuf, 2048, tid, 256);
  size_t base = (size_t)b * NMSM;
  for (int i = tid; i < NMSM; i += 256) {
    unsigned long long v = sbuf[i];
    int m = (int)(~(unsigned)(v & 0xFFFFFFFFull));
    sord[base + i] = m;
    const float* cb = cboxes + (base + m) * 4;
    float off = 4.0f * (float)(m / TOPK + 1);
    float x0 = cb[0] + off, y0 = cb[1] + off, x1 = cb[2] + off, y1 = cb[3] + off;
    sx0[base + i] = x0; sy0[base + i] = y0;
    sx1[base + i] = x1; sy1[base + i] = y1;
    sar[base + i] = (x1 - x0) * (y1 - y0);
  }
  if (tid == 0) nvalid[b] = s_cnt;
}

// ---------------- stage 4b: suppression bitmask ----------------
// NOTE: only upper-triangle chunk pairs (cj >= ci) are WRITTEN. Words cj < ci
// of a mask row are never initialized (0xAA poison) — consumers MUST NOT
// apply them (see wmask in nms_serial_kernel; this is what broke Round 3).
__global__ __launch_bounds__(64) void nms_mask_kernel(
    const float* __restrict__ sx0, const float* __restrict__ sy0,
    const float* __restrict__ sx1, const float* __restrict__ sy1,
    const float* __restrict__ sar, unsigned long long* __restrict__ mask) {
  int b = blockIdx.y;
  int pair = blockIdx.x;
  int ci = 0, rem = pair;
  while (rem >= NCH - ci) { rem -= NCH - ci; ci++; }
  int cj = ci + rem;   // cj >= ci (upper triangle)
  __shared__ float cx0[64], cy0[64], cx1[64], cy1[64], car[64];
  int t = threadIdx.x;
  size_t base = (size_t)b * NMSM;
  int j = cj * 64 + t;
  if (j < NMSM) {
    cx0[t] = sx0[base + j]; cy0[t] = sy0[base + j];
    cx1[t] = sx1[base + j]; cy1[t] = sy1[base + j];
    car[t] = sar[base + j];
  }
  __syncthreads();
  int i = ci * 64 + t;
  if (i >= NMSM) return;
  float x0 = sx0[base + i], y0 = sy0[base + i];
  float x1 = sx1[base + i], y1 = sy1[base + i], a = sar[base + i];
  unsigned long long bits = 0ull;
#pragma unroll 8
  for (int jj = 0; jj < 64; jj++) {
    int jg = cj * 64 + jj;
    float xl = fmaxf(x0, cx0[jj]);
    float yt = fmaxf(y0, cy0[jj]);
    float xr = fminf(x1, cx1[jj]);
    float yb = fminf(y1, cy1[jj]);
    float inter = fmaxf(xr - xl, 0.0f) * fmaxf(yb - yt, 0.0f);
    float iou = inter / (a + car[jj] - inter);
    if (jg > i && jg < NMSM && iou > NMS_THR) bits |= 1ull << jj;
  }
  mask[(base + i) * NCH + cj] = bits;
}

// ---------------- stage 4c: serial greedy reduce + output ----------------
// One wave per image. Lane w (w<22) owns word w of the "alive" bitmask.
// 32-deep STATIC register prefetch ring (slot index compile-time via inner
// unroll-64). Per-iteration critical path ~6 VALU ops on a redundantly-
// maintained copy (cur) of the current alive word, resynced by shfl once/64.
// wmask guards against the UNWRITTEN lower-triangle mask words (Round-3 bug).
__global__ __launch_bounds__(64) void nms_serial_kernel(
    const unsigned long long* __restrict__ mask, const int* __restrict__ sord,
    const int* __restrict__ nvalidArr,
    const float* __restrict__ cboxes, const float* __restrict__ cscores,
    float* __restrict__ out, int B) {
  __shared__ unsigned long long skeep[NCH];
  __shared__ int spfx[NCH];
  int b = blockIdx.x;
  int lane = threadIdx.x;
  int nvalid = nvalidArr[b];
  const unsigned long long* M = mask + (size_t)b * NMSM * NCH;

  // alive bit i=1 for sorted positions < nvalid
  unsigned long long remove = 0ull;
  if (lane < NCH) {
    int base = lane * 64;
    if (base + 64 <= nvalid) remove = ~0ull;
    else if (base < nvalid) remove = (~0ull) >> (64 - (nvalid - base));
  }
  bool act = (lane < NCH);

  // prefetch ring: ring[s] = word `lane` of row i; brow[s] = diagonal word
  // (i>>6) of row i (uniform address -> broadcast). Rows >= NMSM and
  // lower-triangle words read garbage but are never applied.
  unsigned long long ring[RING];
  unsigned long long brow[RING];
#pragma unroll
  for (int d = 0; d < RING; d++) {
    ring[d] = act ? M[(size_t)d * NCH + lane] : 0ull;
    brow[d] = M[(size_t)d * NCH + 0];
  }

  for (int bi = 0; bi < NCH; bi++) {
    unsigned long long cur = __shfl(remove, bi);  // word bi, resync per block
    // only words >= bi of rows in block bi were written by the mask kernel
    unsigned long long wmask = (act && lane >= bi) ? ~0ull : 0ull;
#pragma unroll
    for (int d = 0; d < 64; d++) {
      int i = bi * 64 + d;
      int s = d & (RING - 1);          // compile-time constant
      unsigned long long row = ring[s];
      unsigned long long brw = brow[s];
      int nx = i + RING;               // refill (speculative, guarded by pad)
      ring[s] = act ? M[(size_t)nx * NCH + lane] : 0ull;
      brow[s] = M[(size_t)nx * NCH + (nx >> 6)];
      if ((cur >> d) & 1ull) {         // kept (uniform decision)
        cur &= ~brw;                   // diagonal word: always written
        remove &= ~(row & wmask);      // never apply unwritten words
      }
    }
  }

  if (act) skeep[lane] = remove;
  __syncthreads();
  if (lane == 0) {
    int s = 0;
    for (int w = 0; w < NCH; w++) { spfx[w] = s; s += __popcll(skeep[w]); }
  }
  __syncthreads();

  float* ob = out + (size_t)b * TOPK * 4;
  float* os = out + (size_t)B * TOPK * 4 + (size_t)b * TOPK;
  float* ol = out + (size_t)B * TOPK * 5 + (size_t)b * TOPK;
  for (int r = lane; r < TOPK; r += 64) {
    ob[r * 4 + 0] = 0.0f; ob[r * 4 + 1] = 0.0f;
    ob[r * 4 + 2] = 0.0f; ob[r * 4 + 3] = 0.0f;
    os[r] = 0.0f; ol[r] = 0.0f;
  }
  __syncthreads();
  size_t base = (size_t)b * NMSM;
  for (int i = lane; i < NMSM; i += 64) {
    int w = i >> 6;
    unsigned long long kw = skeep[w];
    if ((kw >> (i & 63)) & 1ull) {
      int r = spfx[w] + __popcll(kw & ((1ull << (i & 63)) - 1ull));
      if (r < TOPK) {
        int m = sord[base + i];
        const float* cb = cboxes + (base + m) * 4;
        ob[r * 4 + 0] = cb[0]; ob[r * 4 + 1] = cb[1];
        ob[r * 4 + 2] = cb[2]; ob[r * 4 + 3] = cb[3];
        os[r] = cscores[base + m];
        ol[r] = (float)(m / TOPK + 1);
      }
    }
  }
}

extern "C" void kernel_launch(void* const* d_in, const int* in_sizes, int n_in,
                              void* d_out, int out_size, void* d_ws, size_t ws_size,
                              hipStream_t stream) {
  const float* logits = (const float*)d_in[0];
  const float* deltas = (const float*)d_in[1];
  const float* dbox   = (const float*)d_in[2];
  int A = in_sizes[2] / 4;
  int B = in_sizes[0] / (A * NCLS);
  float* out = (float*)d_out;

  // workspace layout
  float* scores_ws = (float*)d_ws;                                  // B*7*A floats
  float* tval = scores_ws + (size_t)B * NFG * A;                    // B*7*200
  int*   tidx = (int*)(tval + (size_t)B * NFG * TOPK);              // B*7*200
  float* cboxes = (float*)(tidx + (size_t)B * NFG * TOPK);          // B*1400*4
  float* cscores = cboxes + (size_t)B * NMSM * 4;                   // B*1400

  // NMS scratch aliased onto the scores buffer (dead after topk_kernel):
  //   mask: B*1400*22 u64 = 7.885 MB at offset 0 (serial kernel's speculative
  //   prefetch reads ~0.26 MB past an image's region — still inside 8 MB pad)
  //   sorted arrays at +8 MB (2,097,152 floats)
  unsigned long long* mask = (unsigned long long*)scores_ws;
  float* sbase = scores_ws + 2097152;
  size_t n1 = (size_t)B * NMSM;
  float* sx0 = sbase;            float* sy0 = sbase + n1;
  float* sx1 = sbase + 2 * n1;   float* sy1 = sbase + 3 * n1;
  float* sar = sbase + 4 * n1;
  int*   sord = (int*)(sbase + 5 * n1);
  int*   nvalid = (int*)(sbase + 6 * n1);

  int total = B * A;
  score_kernel<<<(total + 255) / 256, 256, 0, stream>>>(logits, scores_ws, A, total);
  topk_kernel<<<B * NFG, 256, 0, stream>>>(scores_ws, A, tval, tidx);
  int gtotal = B * NMSM;
  gather_kernel<<<(gtotal + 255) / 256, 256, 0, stream>>>(deltas, dbox, tval, tidx,
                                                          cboxes, cscores, A, gtotal);
  nms_sort_kernel<<<B, 256, 0, stream>>>(cboxes, cscores, sx0, sy0, sx1, sy1, sar,
                                         sord, nvalid);
  nms_mask_kernel<<<dim3(NPAIRS, B), 64, 0, stream>>>(sx0, sy0, sx1, sy1, sar, mask);
  nms_serial_kernel<<<B, 64, 0, stream>>>(mask, sord, nvalid, cboxes, cscores, out, B);
}

// Round 5
// 580.983 us; speedup vs baseline: 2.3876x; 1.3426x over previous
//
#include <hip/hip_runtime.h>
#include <hip/hip_bf16.h>
#include <math.h>

// SSD post-processing for MI355X.
// (1) softmax->fg scores [B][7][A]; (2) per-(b,c) top-200 radix-select+bitonic;
// (3) gather+decode selected boxes; (4) NMS: sort -> parallel IoU bitmask ->
// single-wave serial reduce (LDS double-buffered block staging) -> top-200.

#define NCLS 8
#define NFG 7
#define TOPK 200
#define NMSM (NFG * TOPK)   // 1400
#define NCH 22              // ceil(1400/64) 64-wide chunks
#define NPAIRS (NCH * (NCH + 1) / 2)  // 253 upper-triangle chunk pairs
#define BROWS 64
#define BWORDS (BROWS * NCH)          // 1408 u64 per 64-row mask block
#define LOW_SCORE 0.01f
#define NMS_THR 0.45f
#define BINS 4096
#define CAP 4096

// ---------------- stage 1: softmax + transpose ----------------
__global__ __launch_bounds__(256) void score_kernel(
    const float* __restrict__ logits, float* __restrict__ scores, int A, int total) {
  int i = blockIdx.x * 256 + threadIdx.x;   // i = b*A + a
  if (i >= total) return;
  int b = i / A;
  int a = i - b * A;
  const float* p = logits + (size_t)i * NCLS;
  float x[NCLS];
#pragma unroll
  for (int c = 0; c < NCLS; c++) x[c] = p[c];
  float mx = x[0];
#pragma unroll
  for (int c = 1; c < NCLS; c++) mx = fmaxf(mx, x[c]);
  float e[NCLS];
  float s = 0.0f;
#pragma unroll
  for (int c = 0; c < NCLS; c++) { e[c] = expf(x[c] - mx); s += e[c]; }
  float inv = 1.0f / s;
#pragma unroll
  for (int c = 1; c < NCLS; c++) {
    scores[((size_t)b * NFG + (c - 1)) * A + a] = e[c] * inv;
  }
}

// ---------------- bitonic sort (descending) on shared ulong ----------------
__device__ inline void bitonic_desc(unsigned long long* buf, int P, int tid, int nthr) {
  for (int k = 2; k <= P; k <<= 1) {
    for (int j = k >> 1; j > 0; j >>= 1) {
      __syncthreads();
      for (int i = tid; i < P; i += nthr) {
        int l = i ^ j;
        if (l > i) {
          unsigned long long va = buf[i], vb = buf[l];
          bool descRegion = ((i & k) == 0);
          if (descRegion ? (va < vb) : (va > vb)) { buf[i] = vb; buf[l] = va; }
        }
      }
    }
  }
  __syncthreads();
}

// ---------------- stage 2: per-(b,c) top-K ----------------
__global__ __launch_bounds__(256) void topk_kernel(
    const float* __restrict__ scores, int A,
    float* __restrict__ tval, int* __restrict__ tidx) {
  __shared__ unsigned int hist[BINS];
  __shared__ unsigned long long buf[CAP];
  __shared__ int s_t, s_cnt;
  int tid = threadIdx.x;
  int row = blockIdx.x;  // b*7 + c
  const float* p = scores + (size_t)row * A;

  for (int i = tid; i < BINS; i += 256) hist[i] = 0;
  __syncthreads();
  for (int a = tid; a < A; a += 256) {
    unsigned key = __float_as_uint(p[a]);  // scores in (0,1): positive -> order-preserving
    atomicAdd(&hist[key >> 19], 1u);
  }
  __syncthreads();
  if (tid == 0) {
    unsigned cum = 0;
    int t = BINS - 1;
    for (; t >= 0; t--) { cum += hist[t]; if (cum >= TOPK) break; }
    if (t < 0) t = 0;
    s_t = t;
    s_cnt = 0;
  }
  __syncthreads();
  unsigned tbin = (unsigned)s_t;
  for (int a = tid; a < A; a += 256) {
    unsigned key = __float_as_uint(p[a]);
    if ((key >> 19) >= tbin) {
      int pos = atomicAdd(&s_cnt, 1);
      if (pos < CAP)
        buf[pos] = ((unsigned long long)key << 32) | (unsigned)(~a);
    }
  }
  __syncthreads();
  int cnt = s_cnt; if (cnt > CAP) cnt = CAP;
  int P = 256; while (P < cnt) P <<= 1;
  for (int i = cnt + tid; i < P; i += 256) buf[i] = 0ull;
  __syncthreads();
  bitonic_desc(buf, P, tid, 256);
  if (tid < TOPK) {
    unsigned long long v = buf[tid];
    tval[(size_t)row * TOPK + tid] = __uint_as_float((unsigned)(v >> 32));
    tidx[(size_t)row * TOPK + tid] = (int)(~(unsigned)(v & 0xFFFFFFFFull));
  }
}

// ---------------- stage 3: gather + decode ----------------
__global__ __launch_bounds__(256) void gather_kernel(
    const float* __restrict__ deltas, const float* __restrict__ dbox,
    const float* __restrict__ tval, const int* __restrict__ tidx,
    float* __restrict__ cboxes, float* __restrict__ cscores, int A, int total) {
  int i = blockIdx.x * 256 + threadIdx.x;  // b*NMSM + m
  if (i >= total) return;
  int b = i / NMSM;
  int m = i - b * NMSM;
  int c = m / TOPK;
  int r = m - c * TOPK;
  size_t tk = ((size_t)b * NFG + c) * TOPK + r;
  int a = tidx[tk];
  float v = tval[tk];
  const float* db = dbox + (size_t)a * 4;
  float w = db[2] - db[0];
  float h = db[3] - db[1];
  float cx = db[0] + 0.5f * w;
  float cy = db[1] + 0.5f * h;
  const float* dd = deltas + ((size_t)b * A + a) * 4;
  float pcx = dd[0] / 10.0f * w + cx;
  float pcy = dd[1] / 10.0f * h + cy;
  float pw = expf(dd[2] / 5.0f) * w;
  float ph = expf(dd[3] / 5.0f) * h;
  float x0 = fminf(fmaxf(pcx - 0.5f * pw, 0.0f), 1.0f);
  float y0 = fminf(fmaxf(pcy - 0.5f * ph, 0.0f), 1.0f);
  float x1 = fminf(fmaxf(pcx + 0.5f * pw, 0.0f), 1.0f);
  float y1 = fminf(fmaxf(pcy + 0.5f * ph, 0.0f), 1.0f);
  float* cb = cboxes + (size_t)i * 4;
  cb[0] = x0; cb[1] = y0; cb[2] = x1; cb[3] = y1;
  cscores[i] = v;
}

// ---------------- stage 4a: per-image sort ----------------
__global__ __launch_bounds__(256) void nms_sort_kernel(
    const float* __restrict__ cboxes, const float* __restrict__ cscores,
    float* __restrict__ sx0, float* __restrict__ sy0,
    float* __restrict__ sx1, float* __restrict__ sy1,
    float* __restrict__ sar, int* __restrict__ sord, int* __restrict__ nvalid) {
  __shared__ unsigned long long sbuf[2048];
  __shared__ int s_cnt;
  int tid = threadIdx.x;
  int b = blockIdx.x;
  const float* sc = cscores + (size_t)b * NMSM;
  if (tid == 0) s_cnt = 0;
  __syncthreads();
  int myv = 0;
  for (int i = tid; i < 2048; i += 256) {
    unsigned long long v = 0ull;
    if (i < NMSM) {
      float s = sc[i];
      unsigned key = (s > LOW_SCORE) ? __float_as_uint(s) : 0u;
      if (key) myv++;
      v = ((unsigned long long)key << 32) | (unsigned)(~i);
    }
    sbuf[i] = v;
  }
  if (myv) atomicAdd(&s_cnt, myv);
  bitonic_desc(sbuf, 2048, tid, 256);
  size_t base = (size_t)b * NMSM;
  for (int i = tid; i < NMSM; i += 256) {
    unsigned long long v = sbuf[i];
    int m = (int)(~(unsigned)(v & 0xFFFFFFFFull));
    sord[base + i] = m;
    const float* cb = cboxes + (base + m) * 4;
    float off = 4.0f * (float)(m / TOPK + 1);
    float x0 = cb[0] + off, y0 = cb[1] + off, x1 = cb[2] + off, y1 = cb[3] + off;
    sx0[base + i] = x0; sy0[base + i] = y0;
    sx1[base + i] = x1; sy1[base + i] = y1;
    sar[base + i] = (x1 - x0) * (y1 - y0);
  }
  if (tid == 0) nvalid[b] = s_cnt;
}

// ---------------- stage 4b: suppression bitmask ----------------
// NOTE: only upper-triangle chunk pairs (cj >= ci) are WRITTEN. Words cj < ci
// of a mask row are never initialized (0xAA poison) — consumers MUST NOT
// apply them (wmask in nms_serial_kernel; this broke Round 3).
__global__ __launch_bounds__(64) void nms_mask_kernel(
    const float* __restrict__ sx0, const float* __restrict__ sy0,
    const float* __restrict__ sx1, const float* __restrict__ sy1,
    const float* __restrict__ sar, unsigned long long* __restrict__ mask) {
  int b = blockIdx.y;
  int pair = blockIdx.x;
  int ci = 0, rem = pair;
  while (rem >= NCH - ci) { rem -= NCH - ci; ci++; }
  int cj = ci + rem;   // cj >= ci (upper triangle)
  __shared__ float cx0[64], cy0[64], cx1[64], cy1[64], car[64];
  int t = threadIdx.x;
  size_t base = (size_t)b * NMSM;
  int j = cj * 64 + t;
  if (j < NMSM) {
    cx0[t] = sx0[base + j]; cy0[t] = sy0[base + j];
    cx1[t] = sx1[base + j]; cy1[t] = sy1[base + j];
    car[t] = sar[base + j];
  }
  __syncthreads();
  int i = ci * 64 + t;
  if (i >= NMSM) return;
  float x0 = sx0[base + i], y0 = sy0[base + i];
  float x1 = sx1[base + i], y1 = sy1[base + i], a = sar[base + i];
  unsigned long long bits = 0ull;
#pragma unroll 8
  for (int jj = 0; jj < 64; jj++) {
    int jg = cj * 64 + jj;
    float xl = fmaxf(x0, cx0[jj]);
    float yt = fmaxf(y0, cy0[jj]);
    float xr = fminf(x1, cx1[jj]);
    float yb = fminf(y1, cy1[jj]);
    float inter = fmaxf(xr - xl, 0.0f) * fmaxf(yb - yt, 0.0f);
    float iou = inter / (a + car[jj] - inter);
    if (jg > i && jg < NMSM && iou > NMS_THR) bits |= 1ull << jj;
  }
  mask[(base + i) * NCH + cj] = bits;
}

// ---------------- stage 4c: serial greedy reduce + output ----------------
// One wave per image. Lane w (w<22) owns word w of the "alive" bitmask.
// Mask rows of each 64-row block are staged whole into an LDS double buffer
// (cannot spill, unlike Round-2/4 register rings: VGPR_Count=24/72 proved the
// ring lived in scratch -> ~590 cyc/iter). Per block:
//   A: cur = alive word bi (shfl)
//   B: 64-step serial decision chain on diagonal words via readlane (no mem)
//   C: apply kept rows' words to future alive words from LDS (throughput)
//   then issue next block's global->LDS copy (latency hidden by next B/C).
__global__ __launch_bounds__(64) void nms_serial_kernel(
    const unsigned long long* __restrict__ mask, const int* __restrict__ sord,
    const int* __restrict__ nvalidArr,
    const float* __restrict__ cboxes, const float* __restrict__ cscores,
    float* __restrict__ out, int B) {
  __shared__ __align__(16) unsigned long long rowbuf[2][BWORDS + 64];
  __shared__ unsigned long long skeep[NCH];
  __shared__ int spfx[NCH];
  int b = blockIdx.x;
  int lane = threadIdx.x;
  int nvalid = nvalidArr[b];
  const unsigned long long* M = mask + (size_t)b * NMSM * NCH;

  // alive bit i=1 for sorted positions < nvalid
  unsigned long long remove = 0ull;
  if (lane < NCH) {
    int base = lane * 64;
    if (base + 64 <= nvalid) remove = ~0ull;
    else if (base < nvalid) remove = (~0ull) >> (64 - (nvalid - base));
  }
  bool act = (lane < NCH);
  int li = act ? lane : 0;

  // stage block 0 (rows of a block are contiguous: 64*NCH u64)
  {
    const ulonglong2* src = (const ulonglong2*)M;
    ulonglong2* dst = (ulonglong2*)rowbuf[0];
    for (int k = lane; k < BWORDS / 2; k += 64) dst[k] = src[k];
  }
  // single wave: compiler-inserted waitcnts order LDS writes vs reads.

  for (int bi = 0; bi < NCH; bi++) {
    int cb = bi & 1;
    // phase A: current alive word (uniform across lanes)
    unsigned long long cur = __shfl(remove, bi);
    // phase B: serial greedy decisions on diagonal words
    unsigned long long diag = rowbuf[cb][(size_t)lane * NCH + bi];
    unsigned dlo = (unsigned)diag, dhi = (unsigned)(diag >> 32);
#pragma unroll
    for (int d = 0; d < 64; d++) {
      unsigned lo = __builtin_amdgcn_readlane(dlo, d);
      unsigned hi = __builtin_amdgcn_readlane(dhi, d);
      unsigned long long dwd = ((unsigned long long)hi << 32) | lo;
      unsigned long long sel = ((cur >> d) & 1ull) ? dwd : 0ull;
      cur &= ~sel;   // bit d of cur at step d == row kept; final cur == keep word
    }
    // phase C: apply kept rows' mask words to future alive words
    unsigned long long wmask = (act && lane >= bi) ? ~0ull : 0ull;
#pragma unroll 16
    for (int d = 0; d < 64; d++) {
      unsigned long long row = rowbuf[cb][(size_t)d * NCH + li];
      unsigned long long app = ((cur >> d) & 1ull) ? (row & wmask) : 0ull;
      remove &= ~app;
    }
    // commit final word bi (lane bi's diag-applies equal cur by construction)
    remove = (lane == bi) ? cur : remove;
    // prefetch next block into the other LDS buffer (consumed next iteration)
    if (bi + 1 < NCH) {
      const ulonglong2* src = (const ulonglong2*)(M + (size_t)(bi + 1) * BROWS * NCH);
      ulonglong2* dst = (ulonglong2*)rowbuf[cb ^ 1];
      for (int k = lane; k < BWORDS / 2; k += 64) dst[k] = src[k];
    }
  }

  if (act) skeep[lane] = remove;
  __syncthreads();
  if (lane == 0) {
    int s = 0;
    for (int w = 0; w < NCH; w++) { spfx[w] = s; s += __popcll(skeep[w]); }
  }
  __syncthreads();

  float* ob = out + (size_t)b * TOPK * 4;
  float* os = out + (size_t)B * TOPK * 4 + (size_t)b * TOPK;
  float* ol = out + (size_t)B * TOPK * 5 + (size_t)b * TOPK;
  for (int r = lane; r < TOPK; r += 64) {
    ob[r * 4 + 0] = 0.0f; ob[r * 4 + 1] = 0.0f;
    ob[r * 4 + 2] = 0.0f; ob[r * 4 + 3] = 0.0f;
    os[r] = 0.0f; ol[r] = 0.0f;
  }
  __syncthreads();
  size_t base = (size_t)b * NMSM;
  for (int i = lane; i < NMSM; i += 64) {
    int w = i >> 6;
    unsigned long long kw = skeep[w];
    if ((kw >> (i & 63)) & 1ull) {
      int r = spfx[w] + __popcll(kw & ((1ull << (i & 63)) - 1ull));
      if (r < TOPK) {
        int m = sord[base + i];
        const float* cb = cboxes + (base + m) * 4;
        ob[r * 4 + 0] = cb[0]; ob[r * 4 + 1] = cb[1];
        ob[r * 4 + 2] = cb[2]; ob[r * 4 + 3] = cb[3];
        os[r] = cscores[base + m];
        ol[r] = (float)(m / TOPK + 1);
      }
    }
  }
}

extern "C" void kernel_launch(void* const* d_in, const int* in_sizes, int n_in,
                              void* d_out, int out_size, void* d_ws, size_t ws_size,
                              hipStream_t stream) {
  const float* logits = (const float*)d_in[0];
  const float* deltas = (const float*)d_in[1];
  const float* dbox   = (const float*)d_in[2];
  int A = in_sizes[2] / 4;
  int B = in_sizes[0] / (A * NCLS);
  float* out = (float*)d_out;

  // workspace layout
  float* scores_ws = (float*)d_ws;                                  // B*7*A floats
  float* tval = scores_ws + (size_t)B * NFG * A;                    // B*7*200
  int*   tidx = (int*)(tval + (size_t)B * NFG * TOPK);              // B*7*200
  float* cboxes = (float*)(tidx + (size_t)B * NFG * TOPK);          // B*1400*4
  float* cscores = cboxes + (size_t)B * NMSM * 4;                   // B*1400

  // NMS scratch aliased onto the scores buffer (dead after topk_kernel):
  //   mask: B*1400*22 u64 = 7.885 MB at offset 0 (serial kernel's last block
  //   reads 8 padded rows past an image's region — inside the 8 MB window)
  //   sorted arrays at +8 MB (2,097,152 floats)
  unsigned long long* mask = (unsigned long long*)scores_ws;
  float* sbase = scores_ws + 2097152;
  size_t n1 = (size_t)B * NMSM;
  float* sx0 = sbase;            float* sy0 = sbase + n1;
  float* sx1 = sbase + 2 * n1;   float* sy1 = sbase + 3 * n1;
  float* sar = sbase + 4 * n1;
  int*   sord = (int*)(sbase + 5 * n1);
  int*   nvalid = (int*)(sbase + 6 * n1);

  int total = B * A;
  score_kernel<<<(total + 255) / 256, 256, 0, stream>>>(logits, scores_ws, A, total);
  topk_kernel<<<B * NFG, 256, 0, stream>>>(scores_ws, A, tval, tidx);
  int gtotal = B * NMSM;
  gather_kernel<<<(gtotal + 255) / 256, 256, 0, stream>>>(deltas, dbox, tval, tidx,
                                                          cboxes, cscores, A, gtotal);
  nms_sort_kernel<<<B, 256, 0, stream>>>(cboxes, cscores, sx0, sy0, sx1, sy1, sar,
                                         sord, nvalid);
  nms_mask_kernel<<<dim3(NPAIRS, B), 64, 0, stream>>>(sx0, sy0, sx1, sy1, sar, mask);
  nms_serial_kernel<<<B, 64, 0, stream>>>(mask, sord, nvalid, cboxes, cscores, out, B);
}

// Round 6
// 411.399 us; speedup vs baseline: 3.3718x; 1.4122x over previous
//
#include <hip/hip_runtime.h>
#include <hip/hip_bf16.h>
#include <math.h>

// SSD post-processing for MI355X.
// (1) softmax->fg scores [B][7][A]; (2) per-(b,c) top-200: sliced-parallel
// histogram (global ghist) + parallel-suffix-scan select + bitonic sort;
// (3) gather+decode; (4) NMS: sort -> parallel IoU bitmask -> single-wave
// serial reduce (LDS double-buffered block staging) -> top-200 output.

#define NCLS 8
#define NFG 7
#define TOPK 200
#define NMSM (NFG * TOPK)   // 1400
#define NCH 22              // ceil(1400/64) 64-wide chunks
#define NPAIRS (NCH * (NCH + 1) / 2)  // 253 upper-triangle chunk pairs
#define BROWS 64
#define BWORDS (BROWS * NCH)          // 1408 u64 per 64-row mask block
#define NSLICE 8
#define LOW_SCORE 0.01f
#define NMS_THR 0.45f
#define BINS 4096
#define CAP 4096

// ---------------- stage 1: softmax + transpose ----------------
__global__ __launch_bounds__(256) void score_kernel(
    const float* __restrict__ logits, float* __restrict__ scores, int A, int total) {
  int i = blockIdx.x * 256 + threadIdx.x;   // i = b*A + a
  if (i >= total) return;
  int b = i / A;
  int a = i - b * A;
  const float* p = logits + (size_t)i * NCLS;
  float x[NCLS];
#pragma unroll
  for (int c = 0; c < NCLS; c++) x[c] = p[c];
  float mx = x[0];
#pragma unroll
  for (int c = 1; c < NCLS; c++) mx = fmaxf(mx, x[c]);
  float e[NCLS];
  float s = 0.0f;
#pragma unroll
  for (int c = 0; c < NCLS; c++) { e[c] = expf(x[c] - mx); s += e[c]; }
  float inv = 1.0f / s;
#pragma unroll
  for (int c = 1; c < NCLS; c++) {
    scores[((size_t)b * NFG + (c - 1)) * A + a] = e[c] * inv;
  }
}

// ---------------- bitonic sort (descending) on shared ulong ----------------
__device__ inline void bitonic_desc(unsigned long long* buf, int P, int tid, int nthr) {
  for (int k = 2; k <= P; k <<= 1) {
    for (int j = k >> 1; j > 0; j >>= 1) {
      __syncthreads();
      for (int i = tid; i < P; i += nthr) {
        int l = i ^ j;
        if (l > i) {
          unsigned long long va = buf[i], vb = buf[l];
          bool descRegion = ((i & k) == 0);
          if (descRegion ? (va < vb) : (va > vb)) { buf[i] = vb; buf[l] = va; }
        }
      }
    }
  }
  __syncthreads();
}

// ---------------- stage 2a: sliced histogram ----------------
// grid (NROWS, NSLICE). Private LDS hist; flush nonzero bins to global ghist.
__global__ __launch_bounds__(256) void hist_kernel(
    const float* __restrict__ scores, unsigned* __restrict__ ghist, int A) {
  __shared__ unsigned hist[BINS];
  int tid = threadIdx.x;
  int row = blockIdx.x;
  int slice = blockIdx.y;
  int sl = A / NSLICE;                 // 6132, divisible by 4
  for (int i = tid; i < BINS; i += 256) hist[i] = 0;
  __syncthreads();
  const float4* p4 = (const float4*)(scores + (size_t)row * A + (size_t)slice * sl);
  int n4 = sl / 4;
  for (int k = tid; k < n4; k += 256) {
    float4 v = p4[k];
    atomicAdd(&hist[__float_as_uint(v.x) >> 19], 1u);
    atomicAdd(&hist[__float_as_uint(v.y) >> 19], 1u);
    atomicAdd(&hist[__float_as_uint(v.z) >> 19], 1u);
    atomicAdd(&hist[__float_as_uint(v.w) >> 19], 1u);
  }
  __syncthreads();
  unsigned* g = ghist + (size_t)row * BINS;
  for (int i = tid; i < BINS; i += 256) {
    unsigned v = hist[i];
    if (v) atomicAdd(&g[i], v);
  }
}

// ---------------- stage 2b: select threshold + collect + sort ----------------
__global__ __launch_bounds__(256) void select_kernel(
    const float* __restrict__ scores, const unsigned* __restrict__ ghist, int A,
    float* __restrict__ tval, int* __restrict__ tidx) {
  __shared__ unsigned long long buf[CAP];
  __shared__ int sfx[256];
  __shared__ int s_t, s_cnt;
  int tid = threadIdx.x;
  int row = blockIdx.x;  // b*7 + c
  const unsigned* h = ghist + (size_t)row * BINS;
  if (tid == 0) s_cnt = 0;

  // per-thread 16-bin sums, then 8-step suffix scan: sfx[g] = sum bins >= g*16
  int s = 0;
#pragma unroll
  for (int k = 0; k < 16; k++) s += (int)h[tid * 16 + k];
  sfx[tid] = s;
  __syncthreads();
  for (int off = 1; off < 256; off <<= 1) {
    int v = sfx[tid] + ((tid + off < 256) ? sfx[tid + off] : 0);
    __syncthreads();
    sfx[tid] = v;
    __syncthreads();
  }
  // find group g* = max g with sfx[g] >= TOPK, refine within its 16 bins
  // (replicates: scan bins from top, stop when cum >= TOPK; t<0 -> 0)
  if (sfx[0] < TOPK) {
    if (tid == 0) s_t = 0;
  } else {
    bool mine = (sfx[tid] >= TOPK) && (tid == 255 || sfx[tid + 1] < TOPK);
    if (mine) {
      int cum = (tid == 255) ? 0 : sfx[tid + 1];
      int t = tid * 16 + 15;
      for (; t >= tid * 16; t--) { cum += (int)h[t]; if (cum >= TOPK) break; }
      s_t = t;
    }
  }
  __syncthreads();

  // collect candidates (bin >= threshold) with float4 loads
  unsigned tbin = (unsigned)s_t;
  const float4* p4 = (const float4*)(scores + (size_t)row * A);
  int n4 = A / 4;
  for (int k = tid; k < n4; k += 256) {
    float4 v = p4[k];
    float c4[4] = {v.x, v.y, v.z, v.w};
#pragma unroll
    for (int j = 0; j < 4; j++) {
      unsigned key = __float_as_uint(c4[j]);
      if ((key >> 19) >= tbin) {
        int pos = atomicAdd(&s_cnt, 1);
        if (pos < CAP)
          buf[pos] = ((unsigned long long)key << 32) | (unsigned)(~(4 * k + j));
      }
    }
  }
  __syncthreads();
  int cnt = s_cnt; if (cnt > CAP) cnt = CAP;
  int P = 256; while (P < cnt) P <<= 1;
  for (int i = cnt + tid; i < P; i += 256) buf[i] = 0ull;
  __syncthreads();
  bitonic_desc(buf, P, tid, 256);
  if (tid < TOPK) {
    unsigned long long v = buf[tid];
    tval[(size_t)row * TOPK + tid] = __uint_as_float((unsigned)(v >> 32));
    tidx[(size_t)row * TOPK + tid] = (int)(~(unsigned)(v & 0xFFFFFFFFull));
  }
}

// ---------------- stage 3: gather + decode ----------------
__global__ __launch_bounds__(256) void gather_kernel(
    const float* __restrict__ deltas, const float* __restrict__ dbox,
    const float* __restrict__ tval, const int* __restrict__ tidx,
    float* __restrict__ cboxes, float* __restrict__ cscores, int A, int total) {
  int i = blockIdx.x * 256 + threadIdx.x;  // b*NMSM + m
  if (i >= total) return;
  int b = i / NMSM;
  int m = i - b * NMSM;
  int c = m / TOPK;
  int r = m - c * TOPK;
  size_t tk = ((size_t)b * NFG + c) * TOPK + r;
  int a = tidx[tk];
  float v = tval[tk];
  const float* db = dbox + (size_t)a * 4;
  float w = db[2] - db[0];
  float h = db[3] - db[1];
  float cx = db[0] + 0.5f * w;
  float cy = db[1] + 0.5f * h;
  const float* dd = deltas + ((size_t)b * A + a) * 4;
  float pcx = dd[0] / 10.0f * w + cx;
  float pcy = dd[1] / 10.0f * h + cy;
  float pw = expf(dd[2] / 5.0f) * w;
  float ph = expf(dd[3] / 5.0f) * h;
  float x0 = fminf(fmaxf(pcx - 0.5f * pw, 0.0f), 1.0f);
  float y0 = fminf(fmaxf(pcy - 0.5f * ph, 0.0f), 1.0f);
  float x1 = fminf(fmaxf(pcx + 0.5f * pw, 0.0f), 1.0f);
  float y1 = fminf(fmaxf(pcy + 0.5f * ph, 0.0f), 1.0f);
  float* cb = cboxes + (size_t)i * 4;
  cb[0] = x0; cb[1] = y0; cb[2] = x1; cb[3] = y1;
  cscores[i] = v;
}

// ---------------- stage 4a: per-image sort ----------------
__global__ __launch_bounds__(256) void nms_sort_kernel(
    const float* __restrict__ cboxes, const float* __restrict__ cscores,
    float* __restrict__ sx0, float* __restrict__ sy0,
    float* __restrict__ sx1, float* __restrict__ sy1,
    float* __restrict__ sar, int* __restrict__ sord, int* __restrict__ nvalid) {
  __shared__ unsigned long long sbuf[2048];
  __shared__ int s_cnt;
  int tid = threadIdx.x;
  int b = blockIdx.x;
  const float* sc = cscores + (size_t)b * NMSM;
  if (tid == 0) s_cnt = 0;
  __syncthreads();
  int myv = 0;
  for (int i = tid; i < 2048; i += 256) {
    unsigned long long v = 0ull;
    if (i < NMSM) {
      float s = sc[i];
      unsigned key = (s > LOW_SCORE) ? __float_as_uint(s) : 0u;
      if (key) myv++;
      v = ((unsigned long long)key << 32) | (unsigned)(~i);
    }
    sbuf[i] = v;
  }
  if (myv) atomicAdd(&s_cnt, myv);
  bitonic_desc(sbuf, 2048, tid, 256);
  size_t base = (size_t)b * NMSM;
  for (int i = tid; i < NMSM; i += 256) {
    unsigned long long v = sbuf[i];
    int m = (int)(~(unsigned)(v & 0xFFFFFFFFull));
    sord[base + i] = m;
    const float* cb = cboxes + (base + m) * 4;
    float off = 4.0f * (float)(m / TOPK + 1);
    float x0 = cb[0] + off, y0 = cb[1] + off, x1 = cb[2] + off, y1 = cb[3] + off;
    sx0[base + i] = x0; sy0[base + i] = y0;
    sx1[base + i] = x1; sy1[base + i] = y1;
    sar[base + i] = (x1 - x0) * (y1 - y0);
  }
  if (tid == 0) nvalid[b] = s_cnt;
}

// ---------------- stage 4b: suppression bitmask ----------------
// NOTE: only upper-triangle chunk pairs (cj >= ci) are WRITTEN. Words cj < ci
// of a mask row are never initialized (0xAA poison) — consumers MUST NOT
// apply them (wmask in nms_serial_kernel; this broke Round 3).
__global__ __launch_bounds__(64) void nms_mask_kernel(
    const float* __restrict__ sx0, const float* __restrict__ sy0,
    const float* __restrict__ sx1, const float* __restrict__ sy1,
    const float* __restrict__ sar, unsigned long long* __restrict__ mask) {
  int b = blockIdx.y;
  int pair = blockIdx.x;
  int ci = 0, rem = pair;
  while (rem >= NCH - ci) { rem -= NCH - ci; ci++; }
  int cj = ci + rem;   // cj >= ci (upper triangle)
  __shared__ float cx0[64], cy0[64], cx1[64], cy1[64], car[64];
  int t = threadIdx.x;
  size_t base = (size_t)b * NMSM;
  int j = cj * 64 + t;
  if (j < NMSM) {
    cx0[t] = sx0[base + j]; cy0[t] = sy0[base + j];
    cx1[t] = sx1[base + j]; cy1[t] = sy1[base + j];
    car[t] = sar[base + j];
  }
  __syncthreads();
  int i = ci * 64 + t;
  if (i >= NMSM) return;
  float x0 = sx0[base + i], y0 = sy0[base + i];
  float x1 = sx1[base + i], y1 = sy1[base + i], a = sar[base + i];
  unsigned long long bits = 0ull;
#pragma unroll 8
  for (int jj = 0; jj < 64; jj++) {
    int jg = cj * 64 + jj;
    float xl = fmaxf(x0, cx0[jj]);
    float yt = fmaxf(y0, cy0[jj]);
    float xr = fminf(x1, cx1[jj]);
    float yb = fminf(y1, cy1[jj]);
    float inter = fmaxf(xr - xl, 0.0f) * fmaxf(yb - yt, 0.0f);
    float iou = inter / (a + car[jj] - inter);
    if (jg > i && jg < NMSM && iou > NMS_THR) bits |= 1ull << jj;
  }
  mask[(base + i) * NCH + cj] = bits;
}

// ---------------- stage 4c: serial greedy reduce + output ----------------
// One wave per image. Lane w (w<22) owns word w of the "alive" bitmask.
// Mask rows of each 64-row block staged into an LDS double buffer (cannot
// spill). Per block: A) cur = alive word (shfl); B) 64-step serial decision
// chain on diagonal words via readlane (no mem on critical path); C) apply
// kept rows' words from LDS; then issue next block's global->LDS copy.
__global__ __launch_bounds__(64) void nms_serial_kernel(
    const unsigned long long* __restrict__ mask, const int* __restrict__ sord,
    const int* __restrict__ nvalidArr,
    const float* __restrict__ cboxes, const float* __restrict__ cscores,
    float* __restrict__ out, int B) {
  __shared__ __align__(16) unsigned long long rowbuf[2][BWORDS + 64];
  __shared__ unsigned long long skeep[NCH];
  __shared__ int spfx[NCH];
  int b = blockIdx.x;
  int lane = threadIdx.x;
  int nvalid = nvalidArr[b];
  const unsigned long long* M = mask + (size_t)b * NMSM * NCH;

  // alive bit i=1 for sorted positions < nvalid
  unsigned long long remove = 0ull;
  if (lane < NCH) {
    int base = lane * 64;
    if (base + 64 <= nvalid) remove = ~0ull;
    else if (base < nvalid) remove = (~0ull) >> (64 - (nvalid - base));
  }
  bool act = (lane < NCH);
  int li = act ? lane : 0;

  // stage block 0 (rows of a block are contiguous: 64*NCH u64)
  {
    const ulonglong2* src = (const ulonglong2*)M;
    ulonglong2* dst = (ulonglong2*)rowbuf[0];
    for (int k = lane; k < BWORDS / 2; k += 64) dst[k] = src[k];
  }
  // single wave: compiler-inserted waitcnts order LDS writes vs reads.

  for (int bi = 0; bi < NCH; bi++) {
    int cb = bi & 1;
    unsigned long long cur = __shfl(remove, bi);
    unsigned long long diag = rowbuf[cb][(size_t)lane * NCH + bi];
    unsigned dlo = (unsigned)diag, dhi = (unsigned)(diag >> 32);
#pragma unroll
    for (int d = 0; d < 64; d++) {
      unsigned lo = __builtin_amdgcn_readlane(dlo, d);
      unsigned hi = __builtin_amdgcn_readlane(dhi, d);
      unsigned long long dwd = ((unsigned long long)hi << 32) | lo;
      unsigned long long sel = ((cur >> d) & 1ull) ? dwd : 0ull;
      cur &= ~sel;   // final cur == keep word for block bi
    }
    unsigned long long wmask = (act && lane >= bi) ? ~0ull : 0ull;
#pragma unroll 16
    for (int d = 0; d < 64; d++) {
      unsigned long long row = rowbuf[cb][(size_t)d * NCH + li];
      unsigned long long app = ((cur >> d) & 1ull) ? (row & wmask) : 0ull;
      remove &= ~app;
    }
    remove = (lane == bi) ? cur : remove;
    if (bi + 1 < NCH) {
      const ulonglong2* src = (const ulonglong2*)(M + (size_t)(bi + 1) * BROWS * NCH);
      ulonglong2* dst = (ulonglong2*)rowbuf[cb ^ 1];
      for (int k = lane; k < BWORDS / 2; k += 64) dst[k] = src[k];
    }
  }

  if (act) skeep[lane] = remove;
  __syncthreads();
  if (lane == 0) {
    int s = 0;
    for (int w = 0; w < NCH; w++) { spfx[w] = s; s += __popcll(skeep[w]); }
  }
  __syncthreads();

  float* ob = out + (size_t)b * TOPK * 4;
  float* os = out + (size_t)B * TOPK * 4 + (size_t)b * TOPK;
  float* ol = out + (size_t)B * TOPK * 5 + (size_t)b * TOPK;
  for (int r = lane; r < TOPK; r += 64) {
    ob[r * 4 + 0] = 0.0f; ob[r * 4 + 1] = 0.0f;
    ob[r * 4 + 2] = 0.0f; ob[r * 4 + 3] = 0.0f;
    os[r] = 0.0f; ol[r] = 0.0f;
  }
  __syncthreads();
  size_t base = (size_t)b * NMSM;
  for (int i = lane; i < NMSM; i += 64) {
    int w = i >> 6;
    unsigned long long kw = skeep[w];
    if ((kw >> (i & 63)) & 1ull) {
      int r = spfx[w] + __popcll(kw & ((1ull << (i & 63)) - 1ull));
      if (r < TOPK) {
        int m = sord[base + i];
        const float* cb = cboxes + (base + m) * 4;
        ob[r * 4 + 0] = cb[0]; ob[r * 4 + 1] = cb[1];
        ob[r * 4 + 2] = cb[2]; ob[r * 4 + 3] = cb[3];
        os[r] = cscores[base + m];
        ol[r] = (float)(m / TOPK + 1);
      }
    }
  }
}

extern "C" void kernel_launch(void* const* d_in, const int* in_sizes, int n_in,
                              void* d_out, int out_size, void* d_ws, size_t ws_size,
                              hipStream_t stream) {
  const float* logits = (const float*)d_in[0];
  const float* deltas = (const float*)d_in[1];
  const float* dbox   = (const float*)d_in[2];
  int A = in_sizes[2] / 4;
  int B = in_sizes[0] / (A * NCLS);
  int NROWS = B * NFG;
  float* out = (float*)d_out;

  // workspace layout
  float* scores_ws = (float*)d_ws;                                  // B*7*A floats
  float* tval = scores_ws + (size_t)B * NFG * A;                    // B*7*200
  int*   tidx = (int*)(tval + (size_t)B * NFG * TOPK);              // B*7*200
  float* cboxes = (float*)(tidx + (size_t)B * NFG * TOPK);          // B*1400*4
  float* cscores = cboxes + (size_t)B * NMSM * 4;                   // B*1400
  unsigned* ghist = (unsigned*)(cscores + (size_t)B * NMSM);        // 224*4096 u32

  // NMS scratch aliased onto the scores buffer (dead after select_kernel):
  //   mask: B*1400*22 u64 = 7.885 MB at offset 0
  //   sorted arrays at +8 MB (2,097,152 floats)
  unsigned long long* mask = (unsigned long long*)scores_ws;
  float* sbase = scores_ws + 2097152;
  size_t n1 = (size_t)B * NMSM;
  float* sx0 = sbase;            float* sy0 = sbase + n1;
  float* sx1 = sbase + 2 * n1;   float* sy1 = sbase + 3 * n1;
  float* sar = sbase + 4 * n1;
  int*   sord = (int*)(sbase + 5 * n1);
  int*   nvalid = (int*)(sbase + 6 * n1);

  hipMemsetAsync(ghist, 0, (size_t)NROWS * BINS * sizeof(unsigned), stream);
  int total = B * A;
  score_kernel<<<(total + 255) / 256, 256, 0, stream>>>(logits, scores_ws, A, total);
  hist_kernel<<<dim3(NROWS, NSLICE), 256, 0, stream>>>(scores_ws, ghist, A);
  select_kernel<<<NROWS, 256, 0, stream>>>(scores_ws, ghist, A, tval, tidx);
  int gtotal = B * NMSM;
  gather_kernel<<<(gtotal + 255) / 256, 256, 0, stream>>>(deltas, dbox, tval, tidx,
                                                          cboxes, cscores, A, gtotal);
  nms_sort_kernel<<<B, 256, 0, stream>>>(cboxes, cscores, sx0, sy0, sx1, sy1, sar,
                                         sord, nvalid);
  nms_mask_kernel<<<dim3(NPAIRS, B), 64, 0, stream>>>(sx0, sy0, sx1, sy1, sar, mask);
  nms_serial_kernel<<<B, 64, 0, stream>>>(mask, sord, nvalid, cboxes, cscores, out, B);
}

// Round 7
// 363.052 us; speedup vs baseline: 3.8208x; 1.1332x over previous
//
#include <hip/hip_runtime.h>
#include <hip/hip_bf16.h>
#include <math.h>

// SSD post-processing for MI355X.
// (1) softmax->fg scores [B][7][A]; (2) per-(b,c) top-200: sliced-parallel
// histogram (global ghist) + parallel-suffix-scan select + bitonic sort;
// (3) gather+decode; (4) NMS: sort -> parallel IoU bitmask -> single-wave
// serial reduce (software-pipelined LDS staging + scalar greedy chain).

#define NCLS 8
#define NFG 7
#define TOPK 200
#define NMSM (NFG * TOPK)   // 1400
#define NCH 22              // ceil(1400/64) 64-wide chunks
#define NPAIRS (NCH * (NCH + 1) / 2)  // 253 upper-triangle chunk pairs
#define BROWS 64
#define BWORDS (BROWS * NCH)          // 1408 u64 per 64-row mask block
#define NRND 11                       // BWORDS/2/64 ulonglong2 rounds per block
#define NSLICE 8
#define LOW_SCORE 0.01f
#define NMS_THR 0.45f
#define BINS 4096
#define CAP 4096

// ---------------- stage 1: softmax + transpose ----------------
__global__ __launch_bounds__(256) void score_kernel(
    const float* __restrict__ logits, float* __restrict__ scores, int A, int total) {
  int i = blockIdx.x * 256 + threadIdx.x;   // i = b*A + a
  if (i >= total) return;
  int b = i / A;
  int a = i - b * A;
  const float* p = logits + (size_t)i * NCLS;
  float x[NCLS];
#pragma unroll
  for (int c = 0; c < NCLS; c++) x[c] = p[c];
  float mx = x[0];
#pragma unroll
  for (int c = 1; c < NCLS; c++) mx = fmaxf(mx, x[c]);
  float e[NCLS];
  float s = 0.0f;
#pragma unroll
  for (int c = 0; c < NCLS; c++) { e[c] = expf(x[c] - mx); s += e[c]; }
  float inv = 1.0f / s;
#pragma unroll
  for (int c = 1; c < NCLS; c++) {
    scores[((size_t)b * NFG + (c - 1)) * A + a] = e[c] * inv;
  }
}

// ---------------- bitonic sort (descending) on shared ulong ----------------
__device__ inline void bitonic_desc(unsigned long long* buf, int P, int tid, int nthr) {
  for (int k = 2; k <= P; k <<= 1) {
    for (int j = k >> 1; j > 0; j >>= 1) {
      __syncthreads();
      for (int i = tid; i < P; i += nthr) {
        int l = i ^ j;
        if (l > i) {
          unsigned long long va = buf[i], vb = buf[l];
          bool descRegion = ((i & k) == 0);
          if (descRegion ? (va < vb) : (va > vb)) { buf[i] = vb; buf[l] = va; }
        }
      }
    }
  }
  __syncthreads();
}

// ---------------- stage 2a: sliced histogram ----------------
__global__ __launch_bounds__(256) void hist_kernel(
    const float* __restrict__ scores, unsigned* __restrict__ ghist, int A) {
  __shared__ unsigned hist[BINS];
  int tid = threadIdx.x;
  int row = blockIdx.x;
  int slice = blockIdx.y;
  int sl = A / NSLICE;                 // 6132, divisible by 4
  for (int i = tid; i < BINS; i += 256) hist[i] = 0;
  __syncthreads();
  const float4* p4 = (const float4*)(scores + (size_t)row * A + (size_t)slice * sl);
  int n4 = sl / 4;
  for (int k = tid; k < n4; k += 256) {
    float4 v = p4[k];
    atomicAdd(&hist[__float_as_uint(v.x) >> 19], 1u);
    atomicAdd(&hist[__float_as_uint(v.y) >> 19], 1u);
    atomicAdd(&hist[__float_as_uint(v.z) >> 19], 1u);
    atomicAdd(&hist[__float_as_uint(v.w) >> 19], 1u);
  }
  __syncthreads();
  unsigned* g = ghist + (size_t)row * BINS;
  for (int i = tid; i < BINS; i += 256) {
    unsigned v = hist[i];
    if (v) atomicAdd(&g[i], v);
  }
}

// ---------------- stage 2b: select threshold + collect + sort ----------------
__global__ __launch_bounds__(256) void select_kernel(
    const float* __restrict__ scores, const unsigned* __restrict__ ghist, int A,
    float* __restrict__ tval, int* __restrict__ tidx) {
  __shared__ unsigned long long buf[CAP];
  __shared__ int sfx[256];
  __shared__ int s_t, s_cnt;
  int tid = threadIdx.x;
  int row = blockIdx.x;  // b*7 + c
  const unsigned* h = ghist + (size_t)row * BINS;
  if (tid == 0) s_cnt = 0;

  // per-thread 16-bin sums, then 8-step suffix scan: sfx[g] = sum bins >= g*16
  int s = 0;
#pragma unroll
  for (int k = 0; k < 16; k++) s += (int)h[tid * 16 + k];
  sfx[tid] = s;
  __syncthreads();
  for (int off = 1; off < 256; off <<= 1) {
    int v = sfx[tid] + ((tid + off < 256) ? sfx[tid + off] : 0);
    __syncthreads();
    sfx[tid] = v;
    __syncthreads();
  }
  // find group g* = max g with sfx[g] >= TOPK, refine within its 16 bins
  if (sfx[0] < TOPK) {
    if (tid == 0) s_t = 0;
  } else {
    bool mine = (sfx[tid] >= TOPK) && (tid == 255 || sfx[tid + 1] < TOPK);
    if (mine) {
      int cum = (tid == 255) ? 0 : sfx[tid + 1];
      int t = tid * 16 + 15;
      for (; t >= tid * 16; t--) { cum += (int)h[t]; if (cum >= TOPK) break; }
      s_t = t;
    }
  }
  __syncthreads();

  // collect candidates (bin >= threshold) with float4 loads
  unsigned tbin = (unsigned)s_t;
  const float4* p4 = (const float4*)(scores + (size_t)row * A);
  int n4 = A / 4;
  for (int k = tid; k < n4; k += 256) {
    float4 v = p4[k];
    float c4[4] = {v.x, v.y, v.z, v.w};
#pragma unroll
    for (int j = 0; j < 4; j++) {
      unsigned key = __float_as_uint(c4[j]);
      if ((key >> 19) >= tbin) {
        int pos = atomicAdd(&s_cnt, 1);
        if (pos < CAP)
          buf[pos] = ((unsigned long long)key << 32) | (unsigned)(~(4 * k + j));
      }
    }
  }
  __syncthreads();
  int cnt = s_cnt; if (cnt > CAP) cnt = CAP;
  int P = 256; while (P < cnt) P <<= 1;
  for (int i = cnt + tid; i < P; i += 256) buf[i] = 0ull;
  __syncthreads();
  bitonic_desc(buf, P, tid, 256);
  if (tid < TOPK) {
    unsigned long long v = buf[tid];
    tval[(size_t)row * TOPK + tid] = __uint_as_float((unsigned)(v >> 32));
    tidx[(size_t)row * TOPK + tid] = (int)(~(unsigned)(v & 0xFFFFFFFFull));
  }
}

// ---------------- stage 3: gather + decode ----------------
__global__ __launch_bounds__(256) void gather_kernel(
    const float* __restrict__ deltas, const float* __restrict__ dbox,
    const float* __restrict__ tval, const int* __restrict__ tidx,
    float* __restrict__ cboxes, float* __restrict__ cscores, int A, int total) {
  int i = blockIdx.x * 256 + threadIdx.x;  // b*NMSM + m
  if (i >= total) return;
  int b = i / NMSM;
  int m = i - b * NMSM;
  int c = m / TOPK;
  int r = m - c * TOPK;
  size_t tk = ((size_t)b * NFG + c) * TOPK + r;
  int a = tidx[tk];
  float v = tval[tk];
  const float* db = dbox + (size_t)a * 4;
  float w = db[2] - db[0];
  float h = db[3] - db[1];
  float cx = db[0] + 0.5f * w;
  float cy = db[1] + 0.5f * h;
  const float* dd = deltas + ((size_t)b * A + a) * 4;
  float pcx = dd[0] / 10.0f * w + cx;
  float pcy = dd[1] / 10.0f * h + cy;
  float pw = expf(dd[2] / 5.0f) * w;
  float ph = expf(dd[3] / 5.0f) * h;
  float x0 = fminf(fmaxf(pcx - 0.5f * pw, 0.0f), 1.0f);
  float y0 = fminf(fmaxf(pcy - 0.5f * ph, 0.0f), 1.0f);
  float x1 = fminf(fmaxf(pcx + 0.5f * pw, 0.0f), 1.0f);
  float y1 = fminf(fmaxf(pcy + 0.5f * ph, 0.0f), 1.0f);
  float* cb = cboxes + (size_t)i * 4;
  cb[0] = x0; cb[1] = y0; cb[2] = x1; cb[3] = y1;
  cscores[i] = v;
}

// ---------------- stage 4a: per-image sort ----------------
__global__ __launch_bounds__(256) void nms_sort_kernel(
    const float* __restrict__ cboxes, const float* __restrict__ cscores,
    float* __restrict__ sx0, float* __restrict__ sy0,
    float* __restrict__ sx1, float* __restrict__ sy1,
    float* __restrict__ sar, int* __restrict__ sord, int* __restrict__ nvalid) {
  __shared__ unsigned long long sbuf[2048];
  __shared__ int s_cnt;
  int tid = threadIdx.x;
  int b = blockIdx.x;
  const float* sc = cscores + (size_t)b * NMSM;
  if (tid == 0) s_cnt = 0;
  __syncthreads();
  int myv = 0;
  for (int i = tid; i < 2048; i += 256) {
    unsigned long long v = 0ull;
    if (i < NMSM) {
      float s = sc[i];
      unsigned key = (s > LOW_SCORE) ? __float_as_uint(s) : 0u;
      if (key) myv++;
      v = ((unsigned long long)key << 32) | (unsigned)(~i);
    }
    sbuf[i] = v;
  }
  if (myv) atomicAdd(&s_cnt, myv);
  bitonic_desc(sbuf, 2048, tid, 256);
  size_t base = (size_t)b * NMSM;
  for (int i = tid; i < NMSM; i += 256) {
    unsigned long long v = sbuf[i];
    int m = (int)(~(unsigned)(v & 0xFFFFFFFFull));
    sord[base + i] = m;
    const float* cb = cboxes + (base + m) * 4;
    float off = 4.0f * (float)(m / TOPK + 1);
    float x0 = cb[0] + off, y0 = cb[1] + off, x1 = cb[2] + off, y1 = cb[3] + off;
    sx0[base + i] = x0; sy0[base + i] = y0;
    sx1[base + i] = x1; sy1[base + i] = y1;
    sar[base + i] = (x1 - x0) * (y1 - y0);
  }
  if (tid == 0) nvalid[b] = s_cnt;
}

// ---------------- stage 4b: suppression bitmask ----------------
// NOTE: only upper-triangle chunk pairs (cj >= ci) are WRITTEN. Words cj < ci
// of a mask row are never initialized (0xAA poison) — consumers MUST NOT
// apply them (wmask in nms_serial_kernel; this broke Round 3).
__global__ __launch_bounds__(64) void nms_mask_kernel(
    const float* __restrict__ sx0, const float* __restrict__ sy0,
    const float* __restrict__ sx1, const float* __restrict__ sy1,
    const float* __restrict__ sar, unsigned long long* __restrict__ mask) {
  int b = blockIdx.y;
  int pair = blockIdx.x;
  int ci = 0, rem = pair;
  while (rem >= NCH - ci) { rem -= NCH - ci; ci++; }
  int cj = ci + rem;   // cj >= ci (upper triangle)
  __shared__ float cx0[64], cy0[64], cx1[64], cy1[64], car[64];
  int t = threadIdx.x;
  size_t base = (size_t)b * NMSM;
  int j = cj * 64 + t;
  if (j < NMSM) {
    cx0[t] = sx0[base + j]; cy0[t] = sy0[base + j];
    cx1[t] = sx1[base + j]; cy1[t] = sy1[base + j];
    car[t] = sar[base + j];
  }
  __syncthreads();
  int i = ci * 64 + t;
  if (i >= NMSM) return;
  float x0 = sx0[base + i], y0 = sy0[base + i];
  float x1 = sx1[base + i], y1 = sy1[base + i], a = sar[base + i];
  unsigned long long bits = 0ull;
#pragma unroll 8
  for (int jj = 0; jj < 64; jj++) {
    int jg = cj * 64 + jj;
    float xl = fmaxf(x0, cx0[jj]);
    float yt = fmaxf(y0, cy0[jj]);
    float xr = fminf(x1, cx1[jj]);
    float yb = fminf(y1, cy1[jj]);
    float inter = fmaxf(xr - xl, 0.0f) * fmaxf(yb - yt, 0.0f);
    float iou = inter / (a + car[jj] - inter);
    if (jg > i && jg < NMSM && iou > NMS_THR) bits |= 1ull << jj;
  }
  mask[(base + i) * NCH + cj] = bits;
}

// ---------------- stage 4c: serial greedy reduce + output ----------------
// One wave per image. Lane w (w<22) owns word w of the "alive" bitmask.
// Software pipeline per 64-row block: (load next block's 11x ulonglong2 into
// regs, unrolled -> all in flight) | phase B: 64-step SCALAR greedy chain
// (readfirstlane/readlane -> s_cselect+s_andn2) | phase C: pipelined
// ds_read_b64 apply | (ds_write regs -> other LDS buffer). Round-6 version
// issued the copy after phase C with a rolled loop: 11 serialized ~900-cyc
// round-trips/block = the 161 us. Single-wave in-order LDS makes the
// write->read hand-off safe without barriers.
__global__ __launch_bounds__(64) void nms_serial_kernel(
    const unsigned long long* __restrict__ mask, const int* __restrict__ sord,
    const int* __restrict__ nvalidArr,
    const float* __restrict__ cboxes, const float* __restrict__ cscores,
    float* __restrict__ out, int B) {
  __shared__ __align__(16) unsigned long long rowbuf[2][BWORDS + 8];
  __shared__ unsigned long long skeep[NCH];
  __shared__ int spfx[NCH];
  int b = blockIdx.x;
  int lane = threadIdx.x;
  int nvalid = nvalidArr[b];
  const unsigned long long* M = mask + (size_t)b * NMSM * NCH;
  const ulonglong2* gsrc = (const ulonglong2*)M;   // block bi at + bi*BWORDS/2

  // alive bit i=1 for sorted positions < nvalid
  unsigned long long remove = 0ull;
  if (lane < NCH) {
    int base = lane * 64;
    if (base + 64 <= nvalid) remove = ~0ull;
    else if (base < nvalid) remove = (~0ull) >> (64 - (nvalid - base));
  }
  bool act = (lane < NCH);
  int li = act ? lane : 0;

  ulonglong2 tmp[NRND];
  // stage block 0 (unrolled: all loads in flight, one drain)
#pragma unroll
  for (int r = 0; r < NRND; r++) tmp[r] = gsrc[r * 64 + lane];
#pragma unroll
  for (int r = 0; r < NRND; r++) ((ulonglong2*)rowbuf[0])[r * 64 + lane] = tmp[r];

  for (int bi = 0; bi < NCH; bi++) {
    int cb = bi & 1;
    // issue next block's global loads NOW — latency overlaps phases B+C
    if (bi + 1 < NCH) {
#pragma unroll
      for (int r = 0; r < NRND; r++)
        tmp[r] = gsrc[(size_t)(bi + 1) * (BWORDS / 2) + r * 64 + lane];
    }
    // phase A: current alive word -> wave-uniform scalars
    unsigned long long cur = __shfl(remove, bi);
    unsigned clo = __builtin_amdgcn_readfirstlane((unsigned)cur);
    unsigned chi = __builtin_amdgcn_readfirstlane((unsigned)(cur >> 32));
    // phase B: 64-step scalar greedy chain on diagonal words.
    // Row d's diag word has bits only for jj > d, so clearing never touches
    // bits <= d; final (clo,chi) == keep word for this block.
    unsigned long long diag = rowbuf[cb][(size_t)lane * NCH + bi];
    unsigned dlo = (unsigned)diag, dhi = (unsigned)(diag >> 32);
#pragma unroll
    for (int d = 0; d < 64; d++) {
      unsigned lo = __builtin_amdgcn_readlane(dlo, d);
      unsigned hi = __builtin_amdgcn_readlane(dhi, d);
      bool kd = (d < 32) ? ((clo >> d) & 1u) : ((chi >> (d - 32)) & 1u);
      clo &= ~(kd ? lo : 0u);
      chi &= ~(kd ? hi : 0u);
    }
    // phase C: apply kept rows' mask words to future alive words (pipelined)
    unsigned long long wmask = (act && lane >= bi) ? ~0ull : 0ull;
#pragma unroll 16
    for (int d = 0; d < 64; d++) {
      unsigned long long row = rowbuf[cb][(size_t)d * NCH + li];
      bool kd = (d < 32) ? ((clo >> d) & 1u) : ((chi >> (d - 32)) & 1u);
      unsigned long long app = kd ? (row & wmask) : 0ull;
      remove &= ~app;
    }
    unsigned long long cur_final = ((unsigned long long)chi << 32) | clo;
    remove = (lane == bi) ? cur_final : remove;
    // commit next block into the other LDS buffer (consumed next iteration;
    // same-wave LDS ops are in-order, no barrier needed)
    if (bi + 1 < NCH) {
#pragma unroll
      for (int r = 0; r < NRND; r++)
        ((ulonglong2*)rowbuf[cb ^ 1])[r * 64 + lane] = tmp[r];
    }
  }

  if (act) skeep[lane] = remove;
  __syncthreads();
  if (lane == 0) {
    int s = 0;
    for (int w = 0; w < NCH; w++) { spfx[w] = s; s += __popcll(skeep[w]); }
  }
  __syncthreads();

  float* ob = out + (size_t)b * TOPK * 4;
  float* os = out + (size_t)B * TOPK * 4 + (size_t)b * TOPK;
  float* ol = out + (size_t)B * TOPK * 5 + (size_t)b * TOPK;
  for (int r = lane; r < TOPK; r += 64) {
    ob[r * 4 + 0] = 0.0f; ob[r * 4 + 1] = 0.0f;
    ob[r * 4 + 2] = 0.0f; ob[r * 4 + 3] = 0.0f;
    os[r] = 0.0f; ol[r] = 0.0f;
  }
  __syncthreads();
  size_t base = (size_t)b * NMSM;
  for (int i = lane; i < NMSM; i += 64) {
    int w = i >> 6;
    unsigned long long kw = skeep[w];
    if ((kw >> (i & 63)) & 1ull) {
      int r = spfx[w] + __popcll(kw & ((1ull << (i & 63)) - 1ull));
      if (r < TOPK) {
        int m = sord[base + i];
        const float* cb = cboxes + (base + m) * 4;
        ob[r * 4 + 0] = cb[0]; ob[r * 4 + 1] = cb[1];
        ob[r * 4 + 2] = cb[2]; ob[r * 4 + 3] = cb[3];
        os[r] = cscores[base + m];
        ol[r] = (float)(m / TOPK + 1);
      }
    }
  }
}

extern "C" void kernel_launch(void* const* d_in, const int* in_sizes, int n_in,
                              void* d_out, int out_size, void* d_ws, size_t ws_size,
                              hipStream_t stream) {
  const float* logits = (const float*)d_in[0];
  const float* deltas = (const float*)d_in[1];
  const float* dbox   = (const float*)d_in[2];
  int A = in_sizes[2] / 4;
  int B = in_sizes[0] / (A * NCLS);
  int NROWS = B * NFG;
  float* out = (float*)d_out;

  // workspace layout
  float* scores_ws = (float*)d_ws;                                  // B*7*A floats
  float* tval = scores_ws + (size_t)B * NFG * A;                    // B*7*200
  int*   tidx = (int*)(tval + (size_t)B * NFG * TOPK);              // B*7*200
  float* cboxes = (float*)(tidx + (size_t)B * NFG * TOPK);          // B*1400*4
  float* cscores = cboxes + (size_t)B * NMSM * 4;                   // B*1400
  unsigned* ghist = (unsigned*)(cscores + (size_t)B * NMSM);        // 224*4096 u32

  // NMS scratch aliased onto the scores buffer (dead after select_kernel):
  //   mask: B*1400*22 u64 = 7.885 MB at offset 0 (last block reads 8 padded
  //   rows past an image's region — inside the 8 MB window)
  //   sorted arrays at +8 MB (2,097,152 floats)
  unsigned long long* mask = (unsigned long long*)scores_ws;
  float* sbase = scores_ws + 2097152;
  size_t n1 = (size_t)B * NMSM;
  float* sx0 = sbase;            float* sy0 = sbase + n1;
  float* sx1 = sbase + 2 * n1;   float* sy1 = sbase + 3 * n1;
  float* sar = sbase + 4 * n1;
  int*   sord = (int*)(sbase + 5 * n1);
  int*   nvalid = (int*)(sbase + 6 * n1);

  hipMemsetAsync(ghist, 0, (size_t)NROWS * BINS * sizeof(unsigned), stream);
  int total = B * A;
  score_kernel<<<(total + 255) / 256, 256, 0, stream>>>(logits, scores_ws, A, total);
  hist_kernel<<<dim3(NROWS, NSLICE), 256, 0, stream>>>(scores_ws, ghist, A);
  select_kernel<<<NROWS, 256, 0, stream>>>(scores_ws, ghist, A, tval, tidx);
  int gtotal = B * NMSM;
  gather_kernel<<<(gtotal + 255) / 256, 256, 0, stream>>>(deltas, dbox, tval, tidx,
                                                          cboxes, cscores, A, gtotal);
  nms_sort_kernel<<<B, 256, 0, stream>>>(cboxes, cscores, sx0, sy0, sx1, sy1, sar,
                                         sord, nvalid);
  nms_mask_kernel<<<dim3(NPAIRS, B), 64, 0, stream>>>(sx0, sy0, sx1, sy1, sar, mask);
  nms_serial_kernel<<<B, 64, 0, stream>>>(mask, sord, nvalid, cboxes, cscores, out, B);
}

// Round 8
// 347.664 us; speedup vs baseline: 3.9899x; 1.0443x over previous
//
#include <hip/hip_runtime.h>
#include <hip/hip_bf16.h>
#include <math.h>

// SSD post-processing for MI355X.
// (1) softmax->fg scores [B][7][A]; (2) per-(b,c) top-200: sliced-parallel
// histogram (global ghist) + parallel-suffix-scan select + bitonic sort;
// (3) gather+decode; (4) NMS: sort -> parallel IoU bitmask -> 2-wave
// producer/consumer serial reduce (global_load_lds ring) -> top-200 output.

#define NCLS 8
#define NFG 7
#define TOPK 200
#define NMSM (NFG * TOPK)   // 1400
#define NCH 22              // ceil(1400/64) 64-wide chunks
#define NPAIRS (NCH * (NCH + 1) / 2)  // 253 upper-triangle chunk pairs
#define BROWS 64
#define BWORDS (BROWS * NCH)          // 1408 u64 per 64-row mask block
#define NRND 11                       // 1 KB global_load_lds rounds per block
#define NBUF 4                        // LDS ring slots (lead=2, reuse dist 4)
#define NSLICE 8
#define LOW_SCORE 0.01f
#define NMS_THR 0.45f
#define BINS 4096
#define CAP 4096

// ---------------- stage 1: softmax + transpose ----------------
__global__ __launch_bounds__(256) void score_kernel(
    const float* __restrict__ logits, float* __restrict__ scores, int A, int total) {
  int i = blockIdx.x * 256 + threadIdx.x;   // i = b*A + a
  if (i >= total) return;
  int b = i / A;
  int a = i - b * A;
  const float* p = logits + (size_t)i * NCLS;
  float x[NCLS];
#pragma unroll
  for (int c = 0; c < NCLS; c++) x[c] = p[c];
  float mx = x[0];
#pragma unroll
  for (int c = 1; c < NCLS; c++) mx = fmaxf(mx, x[c]);
  float e[NCLS];
  float s = 0.0f;
#pragma unroll
  for (int c = 0; c < NCLS; c++) { e[c] = expf(x[c] - mx); s += e[c]; }
  float inv = 1.0f / s;
#pragma unroll
  for (int c = 1; c < NCLS; c++) {
    scores[((size_t)b * NFG + (c - 1)) * A + a] = e[c] * inv;
  }
}

// ---------------- bitonic sort (descending) on shared ulong ----------------
__device__ inline void bitonic_desc(unsigned long long* buf, int P, int tid, int nthr) {
  for (int k = 2; k <= P; k <<= 1) {
    for (int j = k >> 1; j > 0; j >>= 1) {
      __syncthreads();
      for (int i = tid; i < P; i += nthr) {
        int l = i ^ j;
        if (l > i) {
          unsigned long long va = buf[i], vb = buf[l];
          bool descRegion = ((i & k) == 0);
          if (descRegion ? (va < vb) : (va > vb)) { buf[i] = vb; buf[l] = va; }
        }
      }
    }
  }
  __syncthreads();
}

// ---------------- stage 2a: sliced histogram ----------------
__global__ __launch_bounds__(256) void hist_kernel(
    const float* __restrict__ scores, unsigned* __restrict__ ghist, int A) {
  __shared__ unsigned hist[BINS];
  int tid = threadIdx.x;
  int row = blockIdx.x;
  int slice = blockIdx.y;
  int sl = A / NSLICE;                 // 6132, divisible by 4
  for (int i = tid; i < BINS; i += 256) hist[i] = 0;
  __syncthreads();
  const float4* p4 = (const float4*)(scores + (size_t)row * A + (size_t)slice * sl);
  int n4 = sl / 4;
  for (int k = tid; k < n4; k += 256) {
    float4 v = p4[k];
    atomicAdd(&hist[__float_as_uint(v.x) >> 19], 1u);
    atomicAdd(&hist[__float_as_uint(v.y) >> 19], 1u);
    atomicAdd(&hist[__float_as_uint(v.z) >> 19], 1u);
    atomicAdd(&hist[__float_as_uint(v.w) >> 19], 1u);
  }
  __syncthreads();
  unsigned* g = ghist + (size_t)row * BINS;
  for (int i = tid; i < BINS; i += 256) {
    unsigned v = hist[i];
    if (v) atomicAdd(&g[i], v);
  }
}

// ---------------- stage 2b: select threshold + collect + sort ----------------
__global__ __launch_bounds__(256) void select_kernel(
    const float* __restrict__ scores, const unsigned* __restrict__ ghist, int A,
    float* __restrict__ tval, int* __restrict__ tidx) {
  __shared__ unsigned long long buf[CAP];
  __shared__ int sfx[256];
  __shared__ int s_t, s_cnt;
  int tid = threadIdx.x;
  int row = blockIdx.x;  // b*7 + c
  const unsigned* h = ghist + (size_t)row * BINS;
  if (tid == 0) s_cnt = 0;

  // per-thread 16-bin sums, then 8-step suffix scan: sfx[g] = sum bins >= g*16
  int s = 0;
#pragma unroll
  for (int k = 0; k < 16; k++) s += (int)h[tid * 16 + k];
  sfx[tid] = s;
  __syncthreads();
  for (int off = 1; off < 256; off <<= 1) {
    int v = sfx[tid] + ((tid + off < 256) ? sfx[tid + off] : 0);
    __syncthreads();
    sfx[tid] = v;
    __syncthreads();
  }
  // find group g* = max g with sfx[g] >= TOPK, refine within its 16 bins
  if (sfx[0] < TOPK) {
    if (tid == 0) s_t = 0;
  } else {
    bool mine = (sfx[tid] >= TOPK) && (tid == 255 || sfx[tid + 1] < TOPK);
    if (mine) {
      int cum = (tid == 255) ? 0 : sfx[tid + 1];
      int t = tid * 16 + 15;
      for (; t >= tid * 16; t--) { cum += (int)h[t]; if (cum >= TOPK) break; }
      s_t = t;
    }
  }
  __syncthreads();

  // collect candidates (bin >= threshold) with float4 loads
  unsigned tbin = (unsigned)s_t;
  const float4* p4 = (const float4*)(scores + (size_t)row * A);
  int n4 = A / 4;
  for (int k = tid; k < n4; k += 256) {
    float4 v = p4[k];
    float c4[4] = {v.x, v.y, v.z, v.w};
#pragma unroll
    for (int j = 0; j < 4; j++) {
      unsigned key = __float_as_uint(c4[j]);
      if ((key >> 19) >= tbin) {
        int pos = atomicAdd(&s_cnt, 1);
        if (pos < CAP)
          buf[pos] = ((unsigned long long)key << 32) | (unsigned)(~(4 * k + j));
      }
    }
  }
  __syncthreads();
  int cnt = s_cnt; if (cnt > CAP) cnt = CAP;
  int P = 256; while (P < cnt) P <<= 1;
  for (int i = cnt + tid; i < P; i += 256) buf[i] = 0ull;
  __syncthreads();
  bitonic_desc(buf, P, tid, 256);
  if (tid < TOPK) {
    unsigned long long v = buf[tid];
    tval[(size_t)row * TOPK + tid] = __uint_as_float((unsigned)(v >> 32));
    tidx[(size_t)row * TOPK + tid] = (int)(~(unsigned)(v & 0xFFFFFFFFull));
  }
}

// ---------------- stage 3: gather + decode ----------------
__global__ __launch_bounds__(256) void gather_kernel(
    const float* __restrict__ deltas, const float* __restrict__ dbox,
    const float* __restrict__ tval, const int* __restrict__ tidx,
    float* __restrict__ cboxes, float* __restrict__ cscores, int A, int total) {
  int i = blockIdx.x * 256 + threadIdx.x;  // b*NMSM + m
  if (i >= total) return;
  int b = i / NMSM;
  int m = i - b * NMSM;
  int c = m / TOPK;
  int r = m - c * TOPK;
  size_t tk = ((size_t)b * NFG + c) * TOPK + r;
  int a = tidx[tk];
  float v = tval[tk];
  const float* db = dbox + (size_t)a * 4;
  float w = db[2] - db[0];
  float h = db[3] - db[1];
  float cx = db[0] + 0.5f * w;
  float cy = db[1] + 0.5f * h;
  const float* dd = deltas + ((size_t)b * A + a) * 4;
  float pcx = dd[0] / 10.0f * w + cx;
  float pcy = dd[1] / 10.0f * h + cy;
  float pw = expf(dd[2] / 5.0f) * w;
  float ph = expf(dd[3] / 5.0f) * h;
  float x0 = fminf(fmaxf(pcx - 0.5f * pw, 0.0f), 1.0f);
  float y0 = fminf(fmaxf(pcy - 0.5f * ph, 0.0f), 1.0f);
  float x1 = fminf(fmaxf(pcx + 0.5f * pw, 0.0f), 1.0f);
  float y1 = fminf(fmaxf(pcy + 0.5f * ph, 0.0f), 1.0f);
  float* cb = cboxes + (size_t)i * 4;
  cb[0] = x0; cb[1] = y0; cb[2] = x1; cb[3] = y1;
  cscores[i] = v;
}

// ---------------- stage 4a: per-image sort ----------------
__global__ __launch_bounds__(256) void nms_sort_kernel(
    const float* __restrict__ cboxes, const float* __restrict__ cscores,
    float* __restrict__ sx0, float* __restrict__ sy0,
    float* __restrict__ sx1, float* __restrict__ sy1,
    float* __restrict__ sar, int* __restrict__ sord, int* __restrict__ nvalid) {
  __shared__ unsigned long long sbuf[2048];
  __shared__ int s_cnt;
  int tid = threadIdx.x;
  int b = blockIdx.x;
  const float* sc = cscores + (size_t)b * NMSM;
  if (tid == 0) s_cnt = 0;
  __syncthreads();
  int myv = 0;
  for (int i = tid; i < 2048; i += 256) {
    unsigned long long v = 0ull;
    if (i < NMSM) {
      float s = sc[i];
      unsigned key = (s > LOW_SCORE) ? __float_as_uint(s) : 0u;
      if (key) myv++;
      v = ((unsigned long long)key << 32) | (unsigned)(~i);
    }
    sbuf[i] = v;
  }
  if (myv) atomicAdd(&s_cnt, myv);
  bitonic_desc(sbuf, 2048, tid, 256);
  size_t base = (size_t)b * NMSM;
  for (int i = tid; i < NMSM; i += 256) {
    unsigned long long v = sbuf[i];
    int m = (int)(~(unsigned)(v & 0xFFFFFFFFull));
    sord[base + i] = m;
    const float* cb = cboxes + (base + m) * 4;
    float off = 4.0f * (float)(m / TOPK + 1);
    float x0 = cb[0] + off, y0 = cb[1] + off, x1 = cb[2] + off, y1 = cb[3] + off;
    sx0[base + i] = x0; sy0[base + i] = y0;
    sx1[base + i] = x1; sy1[base + i] = y1;
    sar[base + i] = (x1 - x0) * (y1 - y0);
  }
  if (tid == 0) nvalid[b] = s_cnt;
}

// ---------------- stage 4b: suppression bitmask ----------------
// NOTE: only upper-triangle chunk pairs (cj >= ci) are WRITTEN. Words cj < ci
// of a mask row are never initialized (0xAA poison) — consumers MUST NOT
// apply them (wmask in nms_serial_kernel; this broke Round 3).
__global__ __launch_bounds__(64) void nms_mask_kernel(
    const float* __restrict__ sx0, const float* __restrict__ sy0,
    const float* __restrict__ sx1, const float* __restrict__ sy1,
    const float* __restrict__ sar, unsigned long long* __restrict__ mask) {
  int b = blockIdx.y;
  int pair = blockIdx.x;
  int ci = 0, rem = pair;
  while (rem >= NCH - ci) { rem -= NCH - ci; ci++; }
  int cj = ci + rem;   // cj >= ci (upper triangle)
  __shared__ float cx0[64], cy0[64], cx1[64], cy1[64], car[64];
  int t = threadIdx.x;
  size_t base = (size_t)b * NMSM;
  int j = cj * 64 + t;
  if (j < NMSM) {
    cx0[t] = sx0[base + j]; cy0[t] = sy0[base + j];
    cx1[t] = sx1[base + j]; cy1[t] = sy1[base + j];
    car[t] = sar[base + j];
  }
  __syncthreads();
  int i = ci * 64 + t;
  if (i >= NMSM) return;
  float x0 = sx0[base + i], y0 = sy0[base + i];
  float x1 = sx1[base + i], y1 = sy1[base + i], a = sar[base + i];
  unsigned long long bits = 0ull;
#pragma unroll 8
  for (int jj = 0; jj < 64; jj++) {
    int jg = cj * 64 + jj;
    float xl = fmaxf(x0, cx0[jj]);
    float yt = fmaxf(y0, cy0[jj]);
    float xr = fminf(x1, cx1[jj]);
    float yb = fminf(y1, cy1[jj]);
    float inter = fmaxf(xr - xl, 0.0f) * fmaxf(yb - yt, 0.0f);
    float iou = inter / (a + car[jj] - inter);
    if (jg > i && jg < NMSM && iou > NMS_THR) bits |= 1ull << jj;
  }
  mask[(base + i) * NCH + cj] = bits;
}

// ---------------- stage 4c: producer/consumer serial reduce + output -------
// 128 threads = 2 waves. Wave 1 (producer): per tick t issues 11x
// global_load_lds width-16 for mask block t into ring slot t%4 — no VGPR
// destination, so the register allocator CANNOT sink/serialize the loads
// (Rounds 2/4/7 all lost to that: measured 11x ~900cyc serialized = ~10k
// cyc/block). The mandatory vmcnt(0) drain before s_barrier costs one
// latency and blocks only the producer wave. Wave 0 (consumer): processes
// block t-2 (phases A/B/C as before). __syncthreads per tick; lead 2 < ring
// 4 -> no overwrite; barrier fences LDS-DMA writes before consumer reads.
__global__ __launch_bounds__(128) void nms_serial_kernel(
    const unsigned long long* __restrict__ mask, const int* __restrict__ sord,
    const int* __restrict__ nvalidArr,
    const float* __restrict__ cboxes, const float* __restrict__ cscores,
    float* __restrict__ out, int B) {
  __shared__ __align__(16) unsigned long long rowbuf[NBUF][BWORDS];
  __shared__ unsigned long long skeep[NCH];
  __shared__ int spfx[NCH];
  int b = blockIdx.x;
  int tid = threadIdx.x;
  int wave = tid >> 6;
  int lane = tid & 63;
  int nvalid = nvalidArr[b];
  const unsigned long long* M = mask + (size_t)b * NMSM * NCH;

  // alive bit i=1 for sorted positions < nvalid (consumer wave state)
  unsigned long long remove = 0ull;
  if (wave == 0 && lane < NCH) {
    int base = lane * 64;
    if (base + 64 <= nvalid) remove = ~0ull;
    else if (base < nvalid) remove = (~0ull) >> (64 - (nvalid - base));
  }
  bool act = (lane < NCH);
  int li = act ? lane : 0;

  for (int t = 0; t < NCH + 2; t++) {
    if (wave == 1 && t < NCH) {
      // stage mask block t (contiguous 11,264 B) into ring slot t%4
      const char* src = (const char*)(M + (size_t)t * BWORDS) + lane * 16;
      char* dst = (char*)(rowbuf[t & (NBUF - 1)]) + lane * 16;
#pragma unroll
      for (int r = 0; r < NRND; r++) {
        __builtin_amdgcn_global_load_lds(
            (const __attribute__((address_space(1))) void*)(src + r * 1024),
            (__attribute__((address_space(3))) void*)(dst + r * 1024),
            16, 0, 0);
      }
    }
    if (wave == 0 && t >= 2) {
      int bi = t - 2;
      unsigned long long* rb = rowbuf[bi & (NBUF - 1)];
      // phase A: current alive word -> wave-uniform scalars
      unsigned long long cur = __shfl(remove, bi);
      unsigned clo = __builtin_amdgcn_readfirstlane((unsigned)cur);
      unsigned chi = __builtin_amdgcn_readfirstlane((unsigned)(cur >> 32));
      // phase B: 64-step scalar greedy chain on diagonal words (bits <= d of
      // row d's diag word are 0, so clearing never touches decided bits)
      unsigned long long diag = rb[(size_t)lane * NCH + bi];
      unsigned dlo = (unsigned)diag, dhi = (unsigned)(diag >> 32);
#pragma unroll
      for (int d = 0; d < 64; d++) {
        unsigned lo = __builtin_amdgcn_readlane(dlo, d);
        unsigned hi = __builtin_amdgcn_readlane(dhi, d);
        bool kd = (d < 32) ? ((clo >> d) & 1u) : ((chi >> (d - 32)) & 1u);
        clo &= ~(kd ? lo : 0u);
        chi &= ~(kd ? hi : 0u);
      }
      // phase C: apply kept rows' mask words to future alive words
      unsigned long long wmask = (act && lane >= bi) ? ~0ull : 0ull;
#pragma unroll 16
      for (int d = 0; d < 64; d++) {
        unsigned long long row = rb[(size_t)d * NCH + li];
        bool kd = (d < 32) ? ((clo >> d) & 1u) : ((chi >> (d - 32)) & 1u);
        remove &= ~(kd ? (row & wmask) : 0ull);
      }
      unsigned long long cur_final = ((unsigned long long)chi << 32) | clo;
      remove = (lane == bi) ? cur_final : remove;
    }
    __syncthreads();
  }

  if (wave == 0 && act) skeep[lane] = remove;
  __syncthreads();
  if (tid == 0) {
    int s = 0;
    for (int w = 0; w < NCH; w++) { spfx[w] = s; s += __popcll(skeep[w]); }
  }
  __syncthreads();

  float* ob = out + (size_t)b * TOPK * 4;
  float* os = out + (size_t)B * TOPK * 4 + (size_t)b * TOPK;
  float* ol = out + (size_t)B * TOPK * 5 + (size_t)b * TOPK;
  for (int r = tid; r < TOPK; r += 128) {
    ob[r * 4 + 0] = 0.0f; ob[r * 4 + 1] = 0.0f;
    ob[r * 4 + 2] = 0.0f; ob[r * 4 + 3] = 0.0f;
    os[r] = 0.0f; ol[r] = 0.0f;
  }
  __syncthreads();
  size_t base = (size_t)b * NMSM;
  for (int i = tid; i < NMSM; i += 128) {
    int w = i >> 6;
    unsigned long long kw = skeep[w];
    if ((kw >> (i & 63)) & 1ull) {
      int r = spfx[w] + __popcll(kw & ((1ull << (i & 63)) - 1ull));
      if (r < TOPK) {
        int m = sord[base + i];
        const float* cb = cboxes + (base + m) * 4;
        ob[r * 4 + 0] = cb[0]; ob[r * 4 + 1] = cb[1];
        ob[r * 4 + 2] = cb[2]; ob[r * 4 + 3] = cb[3];
        os[r] = cscores[base + m];
        ol[r] = (float)(m / TOPK + 1);
      }
    }
  }
}

extern "C" void kernel_launch(void* const* d_in, const int* in_sizes, int n_in,
                              void* d_out, int out_size, void* d_ws, size_t ws_size,
                              hipStream_t stream) {
  const float* logits = (const float*)d_in[0];
  const float* deltas = (const float*)d_in[1];
  const float* dbox   = (const float*)d_in[2];
  int A = in_sizes[2] / 4;
  int B = in_sizes[0] / (A * NCLS);
  int NROWS = B * NFG;
  float* out = (float*)d_out;

  // workspace layout
  float* scores_ws = (float*)d_ws;                                  // B*7*A floats
  float* tval = scores_ws + (size_t)B * NFG * A;                    // B*7*200
  int*   tidx = (int*)(tval + (size_t)B * NFG * TOPK);              // B*7*200
  float* cboxes = (float*)(tidx + (size_t)B * NFG * TOPK);          // B*1400*4
  float* cscores = cboxes + (size_t)B * NMSM * 4;                   // B*1400
  unsigned* ghist = (unsigned*)(cscores + (size_t)B * NMSM);        // 224*4096 u32

  // NMS scratch aliased onto the scores buffer (dead after select_kernel):
  //   mask: B*1400*22 u64 = 7.885 MB at offset 0 (last image's last block
  //   stages 8 padded rows = 1.4 KB past its region — inside the 8 MB window)
  //   sorted arrays at +8 MB (2,097,152 floats)
  unsigned long long* mask = (unsigned long long*)scores_ws;
  float* sbase = scores_ws + 2097152;
  size_t n1 = (size_t)B * NMSM;
  float* sx0 = sbase;            float* sy0 = sbase + n1;
  float* sx1 = sbase + 2 * n1;   float* sy1 = sbase + 3 * n1;
  float* sar = sbase + 4 * n1;
  int*   sord = (int*)(sbase + 5 * n1);
  int*   nvalid = (int*)(sbase + 6 * n1);

  hipMemsetAsync(ghist, 0, (size_t)NROWS * BINS * sizeof(unsigned), stream);
  int total = B * A;
  score_kernel<<<(total + 255) / 256, 256, 0, stream>>>(logits, scores_ws, A, total);
  hist_kernel<<<dim3(NROWS, NSLICE), 256, 0, stream>>>(scores_ws, ghist, A);
  select_kernel<<<NROWS, 256, 0, stream>>>(scores_ws, ghist, A, tval, tidx);
  int gtotal = B * NMSM;
  gather_kernel<<<(gtotal + 255) / 256, 256, 0, stream>>>(deltas, dbox, tval, tidx,
                                                          cboxes, cscores, A, gtotal);
  nms_sort_kernel<<<B, 256, 0, stream>>>(cboxes, cscores, sx0, sy0, sx1, sy1, sar,
                                         sord, nvalid);
  nms_mask_kernel<<<dim3(NPAIRS, B), 64, 0, stream>>>(sx0, sy0, sx1, sy1, sar, mask);
  nms_serial_kernel<<<B, 128, 0, stream>>>(mask, sord, nvalid, cboxes, cscores, out, B);
}

// Round 9
// 334.058 us; speedup vs baseline: 4.1525x; 1.0407x over previous
//
#include <hip/hip_runtime.h>
#include <hip/hip_bf16.h>
#include <math.h>

// SSD post-processing for MI355X.
// (1) softmax->fg scores [B][7][A]; (2) per-(b,c) top-200: sliced-parallel
// histogram (global ghist) + parallel-suffix-scan select + bitonic sort;
// (3) gather+decode; (4) NMS: sort -> parallel IoU bitmask -> 2-wave
// producer/consumer serial reduce (global_load_lds ring, UNIFORM lds ptr)
// -> top-200 output.

#define NCLS 8
#define NFG 7
#define TOPK 200
#define NMSM (NFG * TOPK)   // 1400
#define NCH 22              // ceil(1400/64) 64-wide chunks
#define NPAIRS (NCH * (NCH + 1) / 2)  // 253 upper-triangle chunk pairs
#define BROWS 64
#define BWORDS (BROWS * NCH)          // 1408 u64 per 64-row mask block
#define NRND 11                       // 1 KB global_load_lds rounds per block
#define NBUF 4                        // LDS ring slots (lead=2, reuse dist 4)
#define NSLICE 8
#define LOW_SCORE 0.01f
#define NMS_THR 0.45f
#define BINS 4096
#define CAP 4096

// ---------------- stage 1: softmax + transpose ----------------
__global__ __launch_bounds__(256) void score_kernel(
    const float* __restrict__ logits, float* __restrict__ scores, int A, int total) {
  int i = blockIdx.x * 256 + threadIdx.x;   // i = b*A + a
  if (i >= total) return;
  int b = i / A;
  int a = i - b * A;
  const float* p = logits + (size_t)i * NCLS;
  float x[NCLS];
#pragma unroll
  for (int c = 0; c < NCLS; c++) x[c] = p[c];
  float mx = x[0];
#pragma unroll
  for (int c = 1; c < NCLS; c++) mx = fmaxf(mx, x[c]);
  float e[NCLS];
  float s = 0.0f;
#pragma unroll
  for (int c = 0; c < NCLS; c++) { e[c] = expf(x[c] - mx); s += e[c]; }
  float inv = 1.0f / s;
#pragma unroll
  for (int c = 1; c < NCLS; c++) {
    scores[((size_t)b * NFG + (c - 1)) * A + a] = e[c] * inv;
  }
}

// ---------------- bitonic sort (descending) on shared ulong ----------------
__device__ inline void bitonic_desc(unsigned long long* buf, int P, int tid, int nthr) {
  for (int k = 2; k <= P; k <<= 1) {
    for (int j = k >> 1; j > 0; j >>= 1) {
      __syncthreads();
      for (int i = tid; i < P; i += nthr) {
        int l = i ^ j;
        if (l > i) {
          unsigned long long va = buf[i], vb = buf[l];
          bool descRegion = ((i & k) == 0);
          if (descRegion ? (va < vb) : (va > vb)) { buf[i] = vb; buf[l] = va; }
        }
      }
    }
  }
  __syncthreads();
}

// ---------------- stage 2a: sliced histogram ----------------
__global__ __launch_bounds__(256) void hist_kernel(
    const float* __restrict__ scores, unsigned* __restrict__ ghist, int A) {
  __shared__ unsigned hist[BINS];
  int tid = threadIdx.x;
  int row = blockIdx.x;
  int slice = blockIdx.y;
  int sl = A / NSLICE;                 // 6132, divisible by 4
  for (int i = tid; i < BINS; i += 256) hist[i] = 0;
  __syncthreads();
  const float4* p4 = (const float4*)(scores + (size_t)row * A + (size_t)slice * sl);
  int n4 = sl / 4;
  for (int k = tid; k < n4; k += 256) {
    float4 v = p4[k];
    atomicAdd(&hist[__float_as_uint(v.x) >> 19], 1u);
    atomicAdd(&hist[__float_as_uint(v.y) >> 19], 1u);
    atomicAdd(&hist[__float_as_uint(v.z) >> 19], 1u);
    atomicAdd(&hist[__float_as_uint(v.w) >> 19], 1u);
  }
  __syncthreads();
  unsigned* g = ghist + (size_t)row * BINS;
  for (int i = tid; i < BINS; i += 256) {
    unsigned v = hist[i];
    if (v) atomicAdd(&g[i], v);
  }
}

// ---------------- stage 2b: select threshold + collect + sort ----------------
__global__ __launch_bounds__(256) void select_kernel(
    const float* __restrict__ scores, const unsigned* __restrict__ ghist, int A,
    float* __restrict__ tval, int* __restrict__ tidx) {
  __shared__ unsigned long long buf[CAP];
  __shared__ int sfx[256];
  __shared__ int s_t, s_cnt;
  int tid = threadIdx.x;
  int row = blockIdx.x;  // b*7 + c
  const unsigned* h = ghist + (size_t)row * BINS;
  if (tid == 0) s_cnt = 0;

  // per-thread 16-bin sums, then 8-step suffix scan: sfx[g] = sum bins >= g*16
  int s = 0;
#pragma unroll
  for (int k = 0; k < 16; k++) s += (int)h[tid * 16 + k];
  sfx[tid] = s;
  __syncthreads();
  for (int off = 1; off < 256; off <<= 1) {
    int v = sfx[tid] + ((tid + off < 256) ? sfx[tid + off] : 0);
    __syncthreads();
    sfx[tid] = v;
    __syncthreads();
  }
  // find group g* = max g with sfx[g] >= TOPK, refine within its 16 bins
  if (sfx[0] < TOPK) {
    if (tid == 0) s_t = 0;
  } else {
    bool mine = (sfx[tid] >= TOPK) && (tid == 255 || sfx[tid + 1] < TOPK);
    if (mine) {
      int cum = (tid == 255) ? 0 : sfx[tid + 1];
      int t = tid * 16 + 15;
      for (; t >= tid * 16; t--) { cum += (int)h[t]; if (cum >= TOPK) break; }
      s_t = t;
    }
  }
  __syncthreads();

  // collect candidates (bin >= threshold) with float4 loads
  unsigned tbin = (unsigned)s_t;
  const float4* p4 = (const float4*)(scores + (size_t)row * A);
  int n4 = A / 4;
  for (int k = tid; k < n4; k += 256) {
    float4 v = p4[k];
    float c4[4] = {v.x, v.y, v.z, v.w};
#pragma unroll
    for (int j = 0; j < 4; j++) {
      unsigned key = __float_as_uint(c4[j]);
      if ((key >> 19) >= tbin) {
        int pos = atomicAdd(&s_cnt, 1);
        if (pos < CAP)
          buf[pos] = ((unsigned long long)key << 32) | (unsigned)(~(4 * k + j));
      }
    }
  }
  __syncthreads();
  int cnt = s_cnt; if (cnt > CAP) cnt = CAP;
  int P = 256; while (P < cnt) P <<= 1;
  for (int i = cnt + tid; i < P; i += 256) buf[i] = 0ull;
  __syncthreads();
  bitonic_desc(buf, P, tid, 256);
  if (tid < TOPK) {
    unsigned long long v = buf[tid];
    tval[(size_t)row * TOPK + tid] = __uint_as_float((unsigned)(v >> 32));
    tidx[(size_t)row * TOPK + tid] = (int)(~(unsigned)(v & 0xFFFFFFFFull));
  }
}

// ---------------- stage 3: gather + decode ----------------
__global__ __launch_bounds__(256) void gather_kernel(
    const float* __restrict__ deltas, const float* __restrict__ dbox,
    const float* __restrict__ tval, const int* __restrict__ tidx,
    float* __restrict__ cboxes, float* __restrict__ cscores, int A, int total) {
  int i = blockIdx.x * 256 + threadIdx.x;  // b*NMSM + m
  if (i >= total) return;
  int b = i / NMSM;
  int m = i - b * NMSM;
  int c = m / TOPK;
  int r = m - c * TOPK;
  size_t tk = ((size_t)b * NFG + c) * TOPK + r;
  int a = tidx[tk];
  float v = tval[tk];
  const float* db = dbox + (size_t)a * 4;
  float w = db[2] - db[0];
  float h = db[3] - db[1];
  float cx = db[0] + 0.5f * w;
  float cy = db[1] + 0.5f * h;
  const float* dd = deltas + ((size_t)b * A + a) * 4;
  float pcx = dd[0] / 10.0f * w + cx;
  float pcy = dd[1] / 10.0f * h + cy;
  float pw = expf(dd[2] / 5.0f) * w;
  float ph = expf(dd[3] / 5.0f) * h;
  float x0 = fminf(fmaxf(pcx - 0.5f * pw, 0.0f), 1.0f);
  float y0 = fminf(fmaxf(pcy - 0.5f * ph, 0.0f), 1.0f);
  float x1 = fminf(fmaxf(pcx + 0.5f * pw, 0.0f), 1.0f);
  float y1 = fminf(fmaxf(pcy + 0.5f * ph, 0.0f), 1.0f);
  float* cb = cboxes + (size_t)i * 4;
  cb[0] = x0; cb[1] = y0; cb[2] = x1; cb[3] = y1;
  cscores[i] = v;
}

// ---------------- stage 4a: per-image sort ----------------
__global__ __launch_bounds__(256) void nms_sort_kernel(
    const float* __restrict__ cboxes, const float* __restrict__ cscores,
    float* __restrict__ sx0, float* __restrict__ sy0,
    float* __restrict__ sx1, float* __restrict__ sy1,
    float* __restrict__ sar, int* __restrict__ sord, int* __restrict__ nvalid) {
  __shared__ unsigned long long sbuf[2048];
  __shared__ int s_cnt;
  int tid = threadIdx.x;
  int b = blockIdx.x;
  const float* sc = cscores + (size_t)b * NMSM;
  if (tid == 0) s_cnt = 0;
  __syncthreads();
  int myv = 0;
  for (int i = tid; i < 2048; i += 256) {
    unsigned long long v = 0ull;
    if (i < NMSM) {
      float s = sc[i];
      unsigned key = (s > LOW_SCORE) ? __float_as_uint(s) : 0u;
      if (key) myv++;
      v = ((unsigned long long)key << 32) | (unsigned)(~i);
    }
    sbuf[i] = v;
  }
  if (myv) atomicAdd(&s_cnt, myv);
  bitonic_desc(sbuf, 2048, tid, 256);
  size_t base = (size_t)b * NMSM;
  for (int i = tid; i < NMSM; i += 256) {
    unsigned long long v = sbuf[i];
    int m = (int)(~(unsigned)(v & 0xFFFFFFFFull));
    sord[base + i] = m;
    const float* cb = cboxes + (base + m) * 4;
    float off = 4.0f * (float)(m / TOPK + 1);
    float x0 = cb[0] + off, y0 = cb[1] + off, x1 = cb[2] + off, y1 = cb[3] + off;
    sx0[base + i] = x0; sy0[base + i] = y0;
    sx1[base + i] = x1; sy1[base + i] = y1;
    sar[base + i] = (x1 - x0) * (y1 - y0);
  }
  if (tid == 0) nvalid[b] = s_cnt;
}

// ---------------- stage 4b: suppression bitmask ----------------
// NOTE: only upper-triangle chunk pairs (cj >= ci) are WRITTEN. Words cj < ci
// of a mask row are never initialized (0xAA poison) — consumers MUST NOT
// apply them (wmask in nms_serial_kernel; this broke Round 3).
__global__ __launch_bounds__(64) void nms_mask_kernel(
    const float* __restrict__ sx0, const float* __restrict__ sy0,
    const float* __restrict__ sx1, const float* __restrict__ sy1,
    const float* __restrict__ sar, unsigned long long* __restrict__ mask) {
  int b = blockIdx.y;
  int pair = blockIdx.x;
  int ci = 0, rem = pair;
  while (rem >= NCH - ci) { rem -= NCH - ci; ci++; }
  int cj = ci + rem;   // cj >= ci (upper triangle)
  __shared__ float cx0[64], cy0[64], cx1[64], cy1[64], car[64];
  int t = threadIdx.x;
  size_t base = (size_t)b * NMSM;
  int j = cj * 64 + t;
  if (j < NMSM) {
    cx0[t] = sx0[base + j]; cy0[t] = sy0[base + j];
    cx1[t] = sx1[base + j]; cy1[t] = sy1[base + j];
    car[t] = sar[base + j];
  }
  __syncthreads();
  int i = ci * 64 + t;
  if (i >= NMSM) return;
  float x0 = sx0[base + i], y0 = sy0[base + i];
  float x1 = sx1[base + i], y1 = sy1[base + i], a = sar[base + i];
  unsigned long long bits = 0ull;
#pragma unroll 8
  for (int jj = 0; jj < 64; jj++) {
    int jg = cj * 64 + jj;
    float xl = fmaxf(x0, cx0[jj]);
    float yt = fmaxf(y0, cy0[jj]);
    float xr = fminf(x1, cx1[jj]);
    float yb = fminf(y1, cy1[jj]);
    float inter = fmaxf(xr - xl, 0.0f) * fmaxf(yb - yt, 0.0f);
    float iou = inter / (a + car[jj] - inter);
    if (jg > i && jg < NMSM && iou > NMS_THR) bits |= 1ull << jj;
  }
  mask[(base + i) * NCH + cj] = bits;
}

// ---------------- stage 4c: producer/consumer serial reduce + output -------
// 128 threads = 2 waves. Wave 1 (producer): per tick t issues 11x
// global_load_lds width-16 for mask block t into ring slot t%4. The LDS
// destination is WAVE-UNIFORM (slot base + r*1024) — HW adds lane*16 itself.
// Round 8 passed a per-lane-divergent LDS ptr, which the compiler legalized
// with a per-lane waterfall (~8.5k cyc/tick, the whole 84 us). Wave 0
// (consumer): per tick processes block t-2 with a fused per-lane VALU loop:
// broadcast LDS read of the diag word (uniform addr, conflict-free) + own row
// word; chain = bit-test -> cndmask -> andnot (~16 cyc/step), LDS reads
// prefetchable. lead 2 < ring 4 -> no overwrite; barrier fences DMA->reads.
__global__ __launch_bounds__(128) void nms_serial_kernel(
    const unsigned long long* __restrict__ mask, const int* __restrict__ sord,
    const int* __restrict__ nvalidArr,
    const float* __restrict__ cboxes, const float* __restrict__ cscores,
    float* __restrict__ out, int B) {
  __shared__ __align__(16) unsigned long long rowbuf[NBUF][BWORDS];
  __shared__ unsigned long long skeep[NCH];
  __shared__ int spfx[NCH];
  int b = blockIdx.x;
  int tid = threadIdx.x;
  int wave = tid >> 6;
  int lane = tid & 63;
  int nvalid = nvalidArr[b];
  const unsigned long long* M = mask + (size_t)b * NMSM * NCH;

  // alive bit i=1 for sorted positions < nvalid (consumer wave state)
  unsigned long long remove = 0ull;
  if (wave == 0 && lane < NCH) {
    int base = lane * 64;
    if (base + 64 <= nvalid) remove = ~0ull;
    else if (base < nvalid) remove = (~0ull) >> (64 - (nvalid - base));
  }
  bool act = (lane < NCH);
  int li = act ? lane : 0;

  for (int t = 0; t < NCH + 2; t++) {
    if (wave == 1 && t < NCH) {
      // stage mask block t (contiguous 11,264 B) into ring slot t%4.
      // src: per-lane (base + lane*16); dst: WAVE-UNIFORM slot base.
      const char* srcb = (const char*)(M + (size_t)t * BWORDS) + lane * 16;
      char* dstb = (char*)(rowbuf[t & (NBUF - 1)]);
#pragma unroll
      for (int r = 0; r < NRND; r++) {
        __builtin_amdgcn_global_load_lds(
            (const __attribute__((address_space(1))) void*)(srcb + r * 1024),
            (__attribute__((address_space(3))) void*)(dstb + r * 1024),
            16, 0, 0);
      }
    }
    if (wave == 0 && t >= 2) {
      int bi = t - 2;
      unsigned long long* rb = rowbuf[bi & (NBUF - 1)];
      // cur = alive word bi, replicated in ALL lanes (VALU chain, no SALU
      // hazards). Diag words have bits<=d clear, so decided bits are stable.
      unsigned long long cur = __shfl(remove, bi);
      unsigned long long wmask = (act && lane >= bi) ? ~0ull : 0ull;
#pragma unroll 8
      for (int d = 0; d < 64; d++) {
        unsigned long long rowd  = rb[(size_t)d * NCH + li];  // per-lane word
        unsigned long long diagd = rb[(size_t)d * NCH + bi];  // broadcast
        bool kd = (cur >> d) & 1ull;                          // uniform value
        cur    &= ~(kd ? diagd : 0ull);
        remove &= ~(kd ? (rowd & wmask) : 0ull);
      }
      remove = (lane == bi) ? cur : remove;
    }
    __syncthreads();
  }

  if (wave == 0 && act) skeep[lane] = remove;
  __syncthreads();
  if (tid == 0) {
    int s = 0;
    for (int w = 0; w < NCH; w++) { spfx[w] = s; s += __popcll(skeep[w]); }
  }
  __syncthreads();

  float* ob = out + (size_t)b * TOPK * 4;
  float* os = out + (size_t)B * TOPK * 4 + (size_t)b * TOPK;
  float* ol = out + (size_t)B * TOPK * 5 + (size_t)b * TOPK;
  for (int r = tid; r < TOPK; r += 128) {
    ob[r * 4 + 0] = 0.0f; ob[r * 4 + 1] = 0.0f;
    ob[r * 4 + 2] = 0.0f; ob[r * 4 + 3] = 0.0f;
    os[r] = 0.0f; ol[r] = 0.0f;
  }
  __syncthreads();
  size_t base = (size_t)b * NMSM;
  for (int i = tid; i < NMSM; i += 128) {
    int w = i >> 6;
    unsigned long long kw = skeep[w];
    if ((kw >> (i & 63)) & 1ull) {
      int r = spfx[w] + __popcll(kw & ((1ull << (i & 63)) - 1ull));
      if (r < TOPK) {
        int m = sord[base + i];
        const float* cb = cboxes + (base + m) * 4;
        ob[r * 4 + 0] = cb[0]; ob[r * 4 + 1] = cb[1];
        ob[r * 4 + 2] = cb[2]; ob[r * 4 + 3] = cb[3];
        os[r] = cscores[base + m];
        ol[r] = (float)(m / TOPK + 1);
      }
    }
  }
}

extern "C" void kernel_launch(void* const* d_in, const int* in_sizes, int n_in,
                              void* d_out, int out_size, void* d_ws, size_t ws_size,
                              hipStream_t stream) {
  const float* logits = (const float*)d_in[0];
  const float* deltas = (const float*)d_in[1];
  const float* dbox   = (const float*)d_in[2];
  int A = in_sizes[2] / 4;
  int B = in_sizes[0] / (A * NCLS);
  int NROWS = B * NFG;
  float* out = (float*)d_out;

  // workspace layout
  float* scores_ws = (float*)d_ws;                                  // B*7*A floats
  float* tval = scores_ws + (size_t)B * NFG * A;                    // B*7*200
  int*   tidx = (int*)(tval + (size_t)B * NFG * TOPK);              // B*7*200
  float* cboxes = (float*)(tidx + (size_t)B * NFG * TOPK);          // B*1400*4
  float* cscores = cboxes + (size_t)B * NMSM * 4;                   // B*1400
  unsigned* ghist = (unsigned*)(cscores + (size_t)B * NMSM);        // 224*4096 u32

  // NMS scratch aliased onto the scores buffer (dead after select_kernel):
  //   mask: B*1400*22 u64 = 7.885 MB at offset 0 (last image's last block
  //   stages 8 padded rows = 1.4 KB past its region — inside the 8 MB window)
  //   sorted arrays at +8 MB (2,097,152 floats)
  unsigned long long* mask = (unsigned long long*)scores_ws;
  float* sbase = scores_ws + 2097152;
  size_t n1 = (size_t)B * NMSM;
  float* sx0 = sbase;            float* sy0 = sbase + n1;
  float* sx1 = sbase + 2 * n1;   float* sy1 = sbase + 3 * n1;
  float* sar = sbase + 4 * n1;
  int*   sord = (int*)(sbase + 5 * n1);
  int*   nvalid = (int*)(sbase + 6 * n1);

  hipMemsetAsync(ghist, 0, (size_t)NROWS * BINS * sizeof(unsigned), stream);
  int total = B * A;
  score_kernel<<<(total + 255) / 256, 256, 0, stream>>>(logits, scores_ws, A, total);
  hist_kernel<<<dim3(NROWS, NSLICE), 256, 0, stream>>>(scores_ws, ghist, A);
  select_kernel<<<NROWS, 256, 0, stream>>>(scores_ws, ghist, A, tval, tidx);
  int gtotal = B * NMSM;
  gather_kernel<<<(gtotal + 255) / 256, 256, 0, stream>>>(deltas, dbox, tval, tidx,
                                                          cboxes, cscores, A, gtotal);
  nms_sort_kernel<<<B, 256, 0, stream>>>(cboxes, cscores, sx0, sy0, sx1, sy1, sar,
                                         sord, nvalid);
  nms_mask_kernel<<<dim3(NPAIRS, B), 64, 0, stream>>>(sx0, sy0, sx1, sy1, sar, mask);
  nms_serial_kernel<<<B, 128, 0, stream>>>(mask, sord, nvalid, cboxes, cscores, out, B);
}

// Round 10
// 285.885 us; speedup vs baseline: 4.8522x; 1.1685x over previous
//
#include <hip/hip_runtime.h>
#include <hip/hip_bf16.h>
#include <math.h>

// SSD post-processing for MI355X.
// (1) softmax->fg scores [B][7][A]; (2) per-(b,c) top-200: sliced-parallel
// histogram (global ghist) + parallel-suffix-scan select + bitonic sort;
// (3) gather+decode; (4) NMS: merge-rank sort (7 sorted class lists ->
// binary-search ranks) -> parallel IoU bitmask -> 2-wave producer/consumer
// serial reduce (global_load_lds ring, uniform lds ptr) -> top-200 output.

#define NCLS 8
#define NFG 7
#define TOPK 200
#define NMSM (NFG * TOPK)   // 1400
#define NCH 22              // ceil(1400/64) 64-wide chunks
#define NPAIRS (NCH * (NCH + 1) / 2)  // 253 upper-triangle chunk pairs
#define BROWS 64
#define BWORDS (BROWS * NCH)          // 1408 u64 per 64-row mask block
#define NRND 11                       // 1 KB global_load_lds rounds per block
#define NBUF 4                        // LDS ring slots (lead=2, reuse dist 4)
#define NSLICE 8
#define LOW_SCORE 0.01f
#define NMS_THR 0.45f
#define BINS 4096
#define CAP 4096

// ---------------- stage 1: softmax + transpose ----------------
__global__ __launch_bounds__(256) void score_kernel(
    const float* __restrict__ logits, float* __restrict__ scores, int A, int total) {
  int i = blockIdx.x * 256 + threadIdx.x;   // i = b*A + a
  if (i >= total) return;
  int b = i / A;
  int a = i - b * A;
  const float* p = logits + (size_t)i * NCLS;
  float x[NCLS];
#pragma unroll
  for (int c = 0; c < NCLS; c++) x[c] = p[c];
  float mx = x[0];
#pragma unroll
  for (int c = 1; c < NCLS; c++) mx = fmaxf(mx, x[c]);
  float e[NCLS];
  float s = 0.0f;
#pragma unroll
  for (int c = 0; c < NCLS; c++) { e[c] = expf(x[c] - mx); s += e[c]; }
  float inv = 1.0f / s;
#pragma unroll
  for (int c = 1; c < NCLS; c++) {
    scores[((size_t)b * NFG + (c - 1)) * A + a] = e[c] * inv;
  }
}

// ---------------- bitonic sort (descending) on shared ulong ----------------
__device__ inline void bitonic_desc(unsigned long long* buf, int P, int tid, int nthr) {
  for (int k = 2; k <= P; k <<= 1) {
    for (int j = k >> 1; j > 0; j >>= 1) {
      __syncthreads();
      for (int i = tid; i < P; i += nthr) {
        int l = i ^ j;
        if (l > i) {
          unsigned long long va = buf[i], vb = buf[l];
          bool descRegion = ((i & k) == 0);
          if (descRegion ? (va < vb) : (va > vb)) { buf[i] = vb; buf[l] = va; }
        }
      }
    }
  }
  __syncthreads();
}

// ---------------- stage 2a: sliced histogram ----------------
__global__ __launch_bounds__(256) void hist_kernel(
    const float* __restrict__ scores, unsigned* __restrict__ ghist, int A) {
  __shared__ unsigned hist[BINS];
  int tid = threadIdx.x;
  int row = blockIdx.x;
  int slice = blockIdx.y;
  int sl = A / NSLICE;                 // 6132, divisible by 4
  for (int i = tid; i < BINS; i += 256) hist[i] = 0;
  __syncthreads();
  const float4* p4 = (const float4*)(scores + (size_t)row * A + (size_t)slice * sl);
  int n4 = sl / 4;
  for (int k = tid; k < n4; k += 256) {
    float4 v = p4[k];
    atomicAdd(&hist[__float_as_uint(v.x) >> 19], 1u);
    atomicAdd(&hist[__float_as_uint(v.y) >> 19], 1u);
    atomicAdd(&hist[__float_as_uint(v.z) >> 19], 1u);
    atomicAdd(&hist[__float_as_uint(v.w) >> 19], 1u);
  }
  __syncthreads();
  unsigned* g = ghist + (size_t)row * BINS;
  for (int i = tid; i < BINS; i += 256) {
    unsigned v = hist[i];
    if (v) atomicAdd(&g[i], v);
  }
}

// ---------------- stage 2b: select threshold + collect + sort ----------------
__global__ __launch_bounds__(256) void select_kernel(
    const float* __restrict__ scores, const unsigned* __restrict__ ghist, int A,
    float* __restrict__ tval, int* __restrict__ tidx) {
  __shared__ unsigned long long buf[CAP];
  __shared__ int sfx[256];
  __shared__ int s_t, s_cnt;
  int tid = threadIdx.x;
  int row = blockIdx.x;  // b*7 + c
  const unsigned* h = ghist + (size_t)row * BINS;
  if (tid == 0) s_cnt = 0;

  // per-thread 16-bin sums, then 8-step suffix scan: sfx[g] = sum bins >= g*16
  int s = 0;
#pragma unroll
  for (int k = 0; k < 16; k++) s += (int)h[tid * 16 + k];
  sfx[tid] = s;
  __syncthreads();
  for (int off = 1; off < 256; off <<= 1) {
    int v = sfx[tid] + ((tid + off < 256) ? sfx[tid + off] : 0);
    __syncthreads();
    sfx[tid] = v;
    __syncthreads();
  }
  // find group g* = max g with sfx[g] >= TOPK, refine within its 16 bins
  if (sfx[0] < TOPK) {
    if (tid == 0) s_t = 0;
  } else {
    bool mine = (sfx[tid] >= TOPK) && (tid == 255 || sfx[tid + 1] < TOPK);
    if (mine) {
      int cum = (tid == 255) ? 0 : sfx[tid + 1];
      int t = tid * 16 + 15;
      for (; t >= tid * 16; t--) { cum += (int)h[t]; if (cum >= TOPK) break; }
      s_t = t;
    }
  }
  __syncthreads();

  // collect candidates (bin >= threshold) with float4 loads
  unsigned tbin = (unsigned)s_t;
  const float4* p4 = (const float4*)(scores + (size_t)row * A);
  int n4 = A / 4;
  for (int k = tid; k < n4; k += 256) {
    float4 v = p4[k];
    float c4[4] = {v.x, v.y, v.z, v.w};
#pragma unroll
    for (int j = 0; j < 4; j++) {
      unsigned key = __float_as_uint(c4[j]);
      if ((key >> 19) >= tbin) {
        int pos = atomicAdd(&s_cnt, 1);
        if (pos < CAP)
          buf[pos] = ((unsigned long long)key << 32) | (unsigned)(~(4 * k + j));
      }
    }
  }
  __syncthreads();
  int cnt = s_cnt; if (cnt > CAP) cnt = CAP;
  int P = 256; while (P < cnt) P <<= 1;
  for (int i = cnt + tid; i < P; i += 256) buf[i] = 0ull;
  __syncthreads();
  bitonic_desc(buf, P, tid, 256);
  if (tid < TOPK) {
    unsigned long long v = buf[tid];
    tval[(size_t)row * TOPK + tid] = __uint_as_float((unsigned)(v >> 32));
    tidx[(size_t)row * TOPK + tid] = (int)(~(unsigned)(v & 0xFFFFFFFFull));
  }
}

// ---------------- stage 3: gather + decode ----------------
__global__ __launch_bounds__(256) void gather_kernel(
    const float* __restrict__ deltas, const float* __restrict__ dbox,
    const float* __restrict__ tval, const int* __restrict__ tidx,
    float* __restrict__ cboxes, float* __restrict__ cscores, int A, int total) {
  int i = blockIdx.x * 256 + threadIdx.x;  // b*NMSM + m
  if (i >= total) return;
  int b = i / NMSM;
  int m = i - b * NMSM;
  int c = m / TOPK;
  int r = m - c * TOPK;
  size_t tk = ((size_t)b * NFG + c) * TOPK + r;
  int a = tidx[tk];
  float v = tval[tk];
  const float* db = dbox + (size_t)a * 4;
  float w = db[2] - db[0];
  float h = db[3] - db[1];
  float cx = db[0] + 0.5f * w;
  float cy = db[1] + 0.5f * h;
  const float* dd = deltas + ((size_t)b * A + a) * 4;
  float pcx = dd[0] / 10.0f * w + cx;
  float pcy = dd[1] / 10.0f * h + cy;
  float pw = expf(dd[2] / 5.0f) * w;
  float ph = expf(dd[3] / 5.0f) * h;
  float x0 = fminf(fmaxf(pcx - 0.5f * pw, 0.0f), 1.0f);
  float y0 = fminf(fmaxf(pcy - 0.5f * ph, 0.0f), 1.0f);
  float x1 = fminf(fmaxf(pcx + 0.5f * pw, 0.0f), 1.0f);
  float y1 = fminf(fmaxf(pcy + 0.5f * ph, 0.0f), 1.0f);
  float* cb = cboxes + (size_t)i * 4;
  cb[0] = x0; cb[1] = y0; cb[2] = x1; cb[3] = y1;
  cscores[i] = v;
}

// ---------------- stage 4a: per-image merge-rank sort ----------------
// The 1400 candidates are 7 per-class lists, each STRICTLY DESCENDING in the
// composite key (score_bits<<32)|~m (select's bitonic guarantees score
// non-increasing in r; at equal score smaller anchor first -> smaller m ->
// larger ~m). Global sorted position of element e = sum over the 7 lists of
// count(key > key_e) — own list contributes exactly r. 7 independent 8-step
// LDS binary searches per element (unrolled -> registers, ILP hides LDS
// latency). Replaces the 2048-bitonic (66 barrier rounds, 79 us @ 1.3% VALU).
__global__ __launch_bounds__(256) void nms_sort_kernel(
    const float* __restrict__ cboxes, const float* __restrict__ cscores,
    float* __restrict__ sx0, float* __restrict__ sy0,
    float* __restrict__ sx1, float* __restrict__ sy1,
    float* __restrict__ sar, int* __restrict__ sord, int* __restrict__ nvalid) {
  __shared__ unsigned long long keys[NMSM];
  __shared__ int s_cnt;
  int tid = threadIdx.x;
  int b = blockIdx.x;
  const float* sc = cscores + (size_t)b * NMSM;
  if (tid == 0) s_cnt = 0;
  __syncthreads();
  int myv = 0;
  for (int m = tid; m < NMSM; m += 256) {
    float s = sc[m];
    unsigned k32 = (s > LOW_SCORE) ? __float_as_uint(s) : 0u;
    if (k32) myv++;
    keys[m] = ((unsigned long long)k32 << 32) | (unsigned)(~m);
  }
  if (myv) atomicAdd(&s_cnt, myv);
  __syncthreads();

  size_t base = (size_t)b * NMSM;
  for (int m = tid; m < NMSM; m += 256) {
    unsigned long long k = keys[m];
    int c = m / TOPK;
    // rank = sum over all 7 class lists of #(key > k); 7 independent
    // binary searches, fully unrolled (8 steps cover length 200)
    int lo[NFG], hi[NFG];
#pragma unroll
    for (int cc = 0; cc < NFG; cc++) { lo[cc] = 0; hi[cc] = TOPK; }
#pragma unroll
    for (int s8 = 0; s8 < 8; s8++) {
#pragma unroll
      for (int cc = 0; cc < NFG; cc++) {
        if (lo[cc] < hi[cc]) {
          int mid = (lo[cc] + hi[cc]) >> 1;
          if (keys[cc * TOPK + mid] > k) lo[cc] = mid + 1; else hi[cc] = mid;
        }
      }
    }
    int p = 0;
#pragma unroll
    for (int cc = 0; cc < NFG; cc++) p += lo[cc];

    const float* cb = cboxes + (base + m) * 4;
    float off = 4.0f * (float)(c + 1);
    float x0 = cb[0] + off, y0 = cb[1] + off, x1 = cb[2] + off, y1 = cb[3] + off;
    sord[base + p] = m;
    sx0[base + p] = x0; sy0[base + p] = y0;
    sx1[base + p] = x1; sy1[base + p] = y1;
    sar[base + p] = (x1 - x0) * (y1 - y0);
  }
  if (tid == 0) nvalid[b] = s_cnt;
}

// ---------------- stage 4b: suppression bitmask ----------------
// NOTE: only upper-triangle chunk pairs (cj >= ci) are WRITTEN. Words cj < ci
// of a mask row are never initialized (0xAA poison) — consumers MUST NOT
// apply them (wmask in nms_serial_kernel; this broke Round 3).
__global__ __launch_bounds__(64) void nms_mask_kernel(
    const float* __restrict__ sx0, const float* __restrict__ sy0,
    const float* __restrict__ sx1, const float* __restrict__ sy1,
    const float* __restrict__ sar, unsigned long long* __restrict__ mask) {
  int b = blockIdx.y;
  int pair = blockIdx.x;
  int ci = 0, rem = pair;
  while (rem >= NCH - ci) { rem -= NCH - ci; ci++; }
  int cj = ci + rem;   // cj >= ci (upper triangle)
  __shared__ float cx0[64], cy0[64], cx1[64], cy1[64], car[64];
  int t = threadIdx.x;
  size_t base = (size_t)b * NMSM;
  int j = cj * 64 + t;
  if (j < NMSM) {
    cx0[t] = sx0[base + j]; cy0[t] = sy0[base + j];
    cx1[t] = sx1[base + j]; cy1[t] = sy1[base + j];
    car[t] = sar[base + j];
  }
  __syncthreads();
  int i = ci * 64 + t;
  if (i >= NMSM) return;
  float x0 = sx0[base + i], y0 = sy0[base + i];
  float x1 = sx1[base + i], y1 = sy1[base + i], a = sar[base + i];
  unsigned long long bits = 0ull;
#pragma unroll 8
  for (int jj = 0; jj < 64; jj++) {
    int jg = cj * 64 + jj;
    float xl = fmaxf(x0, cx0[jj]);
    float yt = fmaxf(y0, cy0[jj]);
    float xr = fminf(x1, cx1[jj]);
    float yb = fminf(y1, cy1[jj]);
    float inter = fmaxf(xr - xl, 0.0f) * fmaxf(yb - yt, 0.0f);
    float iou = inter / (a + car[jj] - inter);
    if (jg > i && jg < NMSM && iou > NMS_THR) bits |= 1ull << jj;
  }
  mask[(base + i) * NCH + cj] = bits;
}

// ---------------- stage 4c: producer/consumer serial reduce + output -------
// 128 threads = 2 waves. Wave 1 (producer): per tick t issues 11x
// global_load_lds width-16 for mask block t into ring slot t%4 with a
// WAVE-UNIFORM LDS destination (HW adds lane*16; divergent ptr -> waterfall,
// the Round-8 84us). Wave 0 (consumer): per tick processes block t-2 with a
// fused per-lane VALU loop (broadcast diag read + own row word). lead 2 <
// ring 4 -> no overwrite; per-tick barrier fences DMA writes before reads.
__global__ __launch_bounds__(128) void nms_serial_kernel(
    const unsigned long long* __restrict__ mask, const int* __restrict__ sord,
    const int* __restrict__ nvalidArr,
    const float* __restrict__ cboxes, const float* __restrict__ cscores,
    float* __restrict__ out, int B) {
  __shared__ __align__(16) unsigned long long rowbuf[NBUF][BWORDS];
  __shared__ unsigned long long skeep[NCH];
  __shared__ int spfx[NCH];
  int b = blockIdx.x;
  int tid = threadIdx.x;
  int wave = tid >> 6;
  int lane = tid & 63;
  int nvalid = nvalidArr[b];
  const unsigned long long* M = mask + (size_t)b * NMSM * NCH;

  // alive bit i=1 for sorted positions < nvalid (consumer wave state)
  unsigned long long remove = 0ull;
  if (wave == 0 && lane < NCH) {
    int base = lane * 64;
    if (base + 64 <= nvalid) remove = ~0ull;
    else if (base < nvalid) remove = (~0ull) >> (64 - (nvalid - base));
  }
  bool act = (lane < NCH);
  int li = act ? lane : 0;

  for (int t = 0; t < NCH + 2; t++) {
    if (wave == 1 && t < NCH) {
      // stage mask block t (contiguous 11,264 B) into ring slot t%4.
      // src: per-lane (base + lane*16); dst: WAVE-UNIFORM slot base.
      const char* srcb = (const char*)(M + (size_t)t * BWORDS) + lane * 16;
      char* dstb = (char*)(rowbuf[t & (NBUF - 1)]);
#pragma unroll
      for (int r = 0; r < NRND; r++) {
        __builtin_amdgcn_global_load_lds(
            (const __attribute__((address_space(1))) void*)(srcb + r * 1024),
            (__attribute__((address_space(3))) void*)(dstb + r * 1024),
            16, 0, 0);
      }
    }
    if (wave == 0 && t >= 2) {
      int bi = t - 2;
      unsigned long long* rb = rowbuf[bi & (NBUF - 1)];
      // cur = alive word bi, replicated in ALL lanes (VALU chain). Diag words
      // have bits<=d clear, so decided bits are stable.
      unsigned long long cur = __shfl(remove, bi);
      unsigned long long wmask = (act && lane >= bi) ? ~0ull : 0ull;
#pragma unroll 8
      for (int d = 0; d < 64; d++) {
        unsigned long long rowd  = rb[(size_t)d * NCH + li];  // per-lane word
        unsigned long long diagd = rb[(size_t)d * NCH + bi];  // broadcast
        bool kd = (cur >> d) & 1ull;                          // uniform value
        cur    &= ~(kd ? diagd : 0ull);
        remove &= ~(kd ? (rowd & wmask) : 0ull);
      }
      remove = (lane == bi) ? cur : remove;
    }
    __syncthreads();
  }

  if (wave == 0 && act) skeep[lane] = remove;
  __syncthreads();
  if (tid == 0) {
    int s = 0;
    for (int w = 0; w < NCH; w++) { spfx[w] = s; s += __popcll(skeep[w]); }
  }
  __syncthreads();

  float* ob = out + (size_t)b * TOPK * 4;
  float* os = out + (size_t)B * TOPK * 4 + (size_t)b * TOPK;
  float* ol = out + (size_t)B * TOPK * 5 + (size_t)b * TOPK;
  for (int r = tid; r < TOPK; r += 128) {
    ob[r * 4 + 0] = 0.0f; ob[r * 4 + 1] = 0.0f;
    ob[r * 4 + 2] = 0.0f; ob[r * 4 + 3] = 0.0f;
    os[r] = 0.0f; ol[r] = 0.0f;
  }
  __syncthreads();
  size_t base = (size_t)b * NMSM;
  for (int i = tid; i < NMSM; i += 128) {
    int w = i >> 6;
    unsigned long long kw = skeep[w];
    if ((kw >> (i & 63)) & 1ull) {
      int r = spfx[w] + __popcll(kw & ((1ull << (i & 63)) - 1ull));
      if (r < TOPK) {
        int m = sord[base + i];
        const float* cb = cboxes + (base + m) * 4;
        ob[r * 4 + 0] = cb[0]; ob[r * 4 + 1] = cb[1];
        ob[r * 4 + 2] = cb[2]; ob[r * 4 + 3] = cb[3];
        os[r] = cscores[base + m];
        ol[r] = (float)(m / TOPK + 1);
      }
    }
  }
}

extern "C" void kernel_launch(void* const* d_in, const int* in_sizes, int n_in,
                              void* d_out, int out_size, void* d_ws, size_t ws_size,
                              hipStream_t stream) {
  const float* logits = (const float*)d_in[0];
  const float* deltas = (const float*)d_in[1];
  const float* dbox   = (const float*)d_in[2];
  int A = in_sizes[2] / 4;
  int B = in_sizes[0] / (A * NCLS);
  int NROWS = B * NFG;
  float* out = (float*)d_out;

  // workspace layout
  float* scores_ws = (float*)d_ws;                                  // B*7*A floats
  float* tval = scores_ws + (size_t)B * NFG * A;                    // B*7*200
  int*   tidx = (int*)(tval + (size_t)B * NFG * TOPK);              // B*7*200
  float* cboxes = (float*)(tidx + (size_t)B * NFG * TOPK);          // B*1400*4
  float* cscores = cboxes + (size_t)B * NMSM * 4;                   // B*1400
  unsigned* ghist = (unsigned*)(cscores + (size_t)B * NMSM);        // 224*4096 u32

  // NMS scratch aliased onto the scores buffer (dead after select_kernel):
  //   mask: B*1400*22 u64 = 7.885 MB at offset 0 (last image's last block
  //   stages 8 padded rows = 1.4 KB past its region — inside the 8 MB window)
  //   sorted arrays at +8 MB (2,097,152 floats)
  unsigned long long* mask = (unsigned long long*)scores_ws;
  float* sbase = scores_ws + 2097152;
  size_t n1 = (size_t)B * NMSM;
  float* sx0 = sbase;            float* sy0 = sbase + n1;
  float* sx1 = sbase + 2 * n1;   float* sy1 = sbase + 3 * n1;
  float* sar = sbase + 4 * n1;
  int*   sord = (int*)(sbase + 5 * n1);
  int*   nvalid = (int*)(sbase + 6 * n1);

  hipMemsetAsync(ghist, 0, (size_t)NROWS * BINS * sizeof(unsigned), stream);
  int total = B * A;
  score_kernel<<<(total + 255) / 256, 256, 0, stream>>>(logits, scores_ws, A, total);
  hist_kernel<<<dim3(NROWS, NSLICE), 256, 0, stream>>>(scores_ws, ghist, A);
  select_kernel<<<NROWS, 256, 0, stream>>>(scores_ws, ghist, A, tval, tidx);
  int gtotal = B * NMSM;
  gather_kernel<<<(gtotal + 255) / 256, 256, 0, stream>>>(deltas, dbox, tval, tidx,
                                                          cboxes, cscores, A, gtotal);
  nms_sort_kernel<<<B, 256, 0, stream>>>(cboxes, cscores, sx0, sy0, sx1, sy1, sar,
                                         sord, nvalid);
  nms_mask_kernel<<<dim3(NPAIRS, B), 64, 0, stream>>>(sx0, sy0, sx1, sy1, sar, mask);
  nms_serial_kernel<<<B, 128, 0, stream>>>(mask, sord, nvalid, cboxes, cscores, out, B);
}